// Round 12
// baseline (8151.730 us; speedup 1.0000x reference)
//
#include <hip/hip_runtime.h>
#include <math.h>

#define B 128
#define LATENT 512
#define H 1024

typedef unsigned short ushort_t;
typedef unsigned int uint_t;
typedef __bf16 bf16x8 __attribute__((ext_vector_type(8)));
typedef float f32x4 __attribute__((ext_vector_type(4)));

// ---------------- common small kernels ----------------

__global__ __launch_bounds__(256) void zero4_kernel(float4* __restrict__ p, int n4) {
  int i = blockIdx.x * blockDim.x + threadIdx.x;
  int stride = gridDim.x * blockDim.x;
  float4 z = {0.f, 0.f, 0.f, 0.f};
  for (; i < n4; i += stride) p[i] = z;
}

__device__ __forceinline__ void split_bf16(float f, ushort_t& h, ushort_t& l) {
  uint_t u = __float_as_uint(f);
  uint_t hb = (u + 0x7FFFu + ((u >> 16) & 1u)) >> 16;
  float fh = __uint_as_float(hb << 16);
  float r = f - fh;
  uint_t v = __float_as_uint(r);
  uint_t lb = (v + 0x7FFFu + ((v >> 16) & 1u)) >> 16;
  h = (ushort_t)hb; l = (ushort_t)lb;
}

__global__ __launch_bounds__(256) void split_kernel(const float* __restrict__ src,
                                                    ushort_t* __restrict__ hi,
                                                    ushort_t* __restrict__ lo, int n) {
  int i = blockIdx.x * blockDim.x + threadIdx.x;
  int stride = gridDim.x * blockDim.x;
  for (; i < n; i += stride) {
    ushort_t h, l;
    split_bf16(src[i], h, l);
    hi[i] = h; lo[i] = l;
  }
}

// hi-only (round-to-nearest-even bf16) for weights
__global__ __launch_bounds__(256) void split_hi_kernel(const float* __restrict__ src,
                                                       ushort_t* __restrict__ hi, int n) {
  int i = blockIdx.x * blockDim.x + threadIdx.x;
  int stride = gridDim.x * blockDim.x;
  for (; i < n; i += stride) {
    uint_t u = __float_as_uint(src[i]);
    hi[i] = (ushort_t)((u + 0x7FFFu + ((u >> 16) & 1u)) >> 16);
  }
}

__device__ __forceinline__ float sigmoidf_(float v) { return 1.0f / (1.0f + expf(-v)); }

// ---------------- per-GROUP barrier (32 blocks; group g = bid&7) ----------------
// 1KB (256 uints) per group: arrival sub-line (m&7)*16, master at 8*16, release
// at 9*16. Generation-based, replay-safe. Under round-robin dispatch all of a
// group's blocks live on one XCD -> all lines stay in that XCD's L2.
__device__ __forceinline__ void group_barrier(unsigned* bar, int tid, int g, int m) {
  __syncthreads();
  if (tid == 0) {
    unsigned* base   = bar + g * 256;
    unsigned* arr    = base + (m & 7) * 16;
    unsigned* master = base + 8 * 16;
    unsigned* rel    = base + 9 * 16;
    unsigned gen = __hip_atomic_load(rel, __ATOMIC_RELAXED, __HIP_MEMORY_SCOPE_AGENT);
    unsigned a = __hip_atomic_fetch_add(arr, 1u, __ATOMIC_ACQ_REL, __HIP_MEMORY_SCOPE_AGENT);
    if (a == 3u) {
      __hip_atomic_store(arr, 0u, __ATOMIC_RELAXED, __HIP_MEMORY_SCOPE_AGENT);
      unsigned mm = __hip_atomic_fetch_add(master, 1u, __ATOMIC_ACQ_REL, __HIP_MEMORY_SCOPE_AGENT);
      if (mm == 7u) {
        __hip_atomic_store(master, 0u, __ATOMIC_RELAXED, __HIP_MEMORY_SCOPE_AGENT);
        __hip_atomic_fetch_add(rel, 1u, __ATOMIC_ACQ_REL, __HIP_MEMORY_SCOPE_AGENT);
      }
    }
    while (__hip_atomic_load(rel, __ATOMIC_RELAXED, __HIP_MEMORY_SCOPE_AGENT) == gen)
      __builtin_amdgcn_s_sleep(1);
    (void)__hip_atomic_load(rel, __ATOMIC_ACQUIRE, __HIP_MEMORY_SCOPE_AGENT);
  }
  __syncthreads();
}

// ---------------- one GEMM phase (group-local; 16 rows x NJ*16 cols x NG gates) ----------------
// 2-term numerics: acc = xh*wh + xl*wh (exact x, bf16 W) — same order as round 11.
// Staging: round-6 double-buffered global_load_lds, 1 __syncthreads/chunk.
template <int NJ, int NG, int PH, int EPI>
__device__ __forceinline__ void phase_mm(
    char* smem, const int tid, const int g, const int m,
    const ushort_t* aAh, const ushort_t* aAl, int aApitch, int K1,
    const ushort_t* wAh,
    const ushort_t* aBh, const ushort_t* aBl, int aBpitch, int K2,
    const ushort_t* wBh,
    const float* bih, const float* bhh,
    const float* h_prev, float* h_out,
    ushort_t* out_hi, ushort_t* out_lo, int split_pitch,
    const float* bias, float* out_f32, int out_pitch)
{
  constexpr int NSLOT = 2 + NJ * NG;     // A hi,lo + W tiles
  constexpr int BUFB  = NSLOT * 4096;
  constexpr int NPG   = NJ * NG * PH;    // acc sets per lane
  constexpr int CW    = NJ * 16;         // cols per block

  const int b0 = g * 16;
  const int j0 = m * CW;

  const int NC1 = K1 >> 7;
  const int NC2 = (PH == 2) ? (K2 >> 7) : 0;
  const int NC = NC1 + NC2;

  const char* gptr[NSLOT];
  auto build = [&](const ushort_t* ah, const ushort_t* al, int apitch,
                   const ushort_t* wh, int K) {
    const int row = tid >> 4;
    const int cp  = tid & 15;
    const int cc  = cp ^ row;            // swizzled granule
    #pragma unroll
    for (int u = 0; u < NSLOT; ++u) {
      const ushort_t* basep; size_t off;
      if (u == 0)      { basep = ah; off = (size_t)(b0 + row) * apitch + cc * 8; }
      else if (u == 1) { basep = al; off = (size_t)(b0 + row) * apitch + cc * 8; }
      else {
        const int w = u - 2;
        const int jt = w % NJ, gate = w / NJ;
        const int wrow = (NG == 3) ? (gate * H + j0 + jt * 16 + row) : (j0 + jt * 16 + row);
        basep = wh; off = (size_t)wrow * K + cc * 8;
      }
      gptr[u] = (const char*)(basep + off);
    }
  };

  // fragment read offsets
  const int s = tid >> 6;
  const int q = (tid >> 4) & 3;
  const int r = tid & 15;
  const int gs = (((4 * s + q) ^ r) << 4);
  const int offA0 = r * 256 + gs;
  const int offA1 = 4096 + r * 256 + gs;
  int offW[NJ * NG];
  #pragma unroll
  for (int w = 0; w < NJ * NG; ++w)
    offW[w] = (2 + w) * 4096 + r * 256 + gs;

  f32x4 accA[NJ][NG];
  f32x4 accB[NJ][NG];
  #pragma unroll
  for (int jt = 0; jt < NJ; ++jt)
    #pragma unroll
    for (int gg = 0; gg < NG; ++gg) {
      accA[jt][gg] = (f32x4){0.f, 0.f, 0.f, 0.f};
      accB[jt][gg] = (f32x4){0.f, 0.f, 0.f, 0.f};
    }

  const unsigned wofs = (unsigned)(tid >> 6) * 1024;
  auto issue = [&](int bsel, int koff) {
    #pragma unroll
    for (int u = 0; u < NSLOT; ++u) {
      __builtin_amdgcn_global_load_lds(
          (const __attribute__((address_space(1))) void*)(gptr[u] + koff),
          (__attribute__((address_space(3))) void*)(smem + bsel * BUFB + u * 4096 + wofs),
          16, 0, 0);
    }
  };

  auto compute = [&](int bsel, f32x4 (&acc)[NJ][NG]) {
    const char* base = smem + bsel * BUFB;
    bf16x8 ah = *(const bf16x8*)(base + offA0);
    bf16x8 al = *(const bf16x8*)(base + offA1);
    #pragma unroll
    for (int gg = 0; gg < NG; ++gg)
      #pragma unroll
      for (int jt = 0; jt < NJ; ++jt) {
        bf16x8 wv = *(const bf16x8*)(base + offW[gg * NJ + jt]);
        acc[jt][gg] = __builtin_amdgcn_mfma_f32_16x16x32_bf16(ah, wv, acc[jt][gg], 0, 0, 0);
        acc[jt][gg] = __builtin_amdgcn_mfma_f32_16x16x32_bf16(al, wv, acc[jt][gg], 0, 0, 0);
      }
  };

  // prologue
  build(aAh, aAl, aApitch, wAh, K1);
  issue(0, 0);

  #pragma unroll 1
  for (int c = 0; c < NC; ++c) {
    __syncthreads();               // chunk-c staging landed; prior reads done
    if (c + 1 < NC) {
      if (PH == 2 && c + 1 == NC1) {
        build(aBh, aBl, aBpitch, wBh, K2);
        issue((c + 1) & 1, 0);
      } else {
        int koff = ((c + 1 >= NC1 && PH == 2) ? (c + 1 - NC1) : (c + 1)) * 256;
        issue((c + 1) & 1, koff);
      }
    }
    if (PH == 1 || c < NC1) compute(c & 1, accA);
    else                    compute(c & 1, accB);
  }
  __syncthreads();

  // ---- cross-wave reduce (alias smem) ----
  const int lane = tid & 63;
  #pragma unroll
  for (int gg = 0; gg < NG; ++gg)
    #pragma unroll
    for (int jt = 0; jt < NJ; ++jt) {
      *(f32x4*)(smem + (((s * NPG + gg * NJ + jt) * 64 + lane) * 16)) = accA[jt][gg];
      if (PH == 2)
        *(f32x4*)(smem + (((s * NPG + (NG + gg) * NJ + jt) * 64 + lane) * 16)) = accB[jt][gg];
    }
  __syncthreads();

  for (int o = tid; o < 16 * CW; o += 256) {
    const int row = o / CW, c = o % CW;
    const int jt = c >> 4, cr = c & 15;
    const int qq = row >> 2, rg = row & 3;
    const int ln = cr + qq * 16;
    float v[PH * NG];
    #pragma unroll
    for (int pg = 0; pg < PH * NG; ++pg) {
      float sum = 0.f;
      #pragma unroll
      for (int ss = 0; ss < 4; ++ss)
        sum += *(const float*)(smem + (((ss * NPG + pg * NJ + jt) * 64 + ln) * 16 + rg * 4));
      v[pg] = sum;
    }
    const int bglob = b0 + row, jglob = j0 + c;
    if (EPI == 0) {
      float ir = v[0] + bih[jglob];
      float iz = v[1] + bih[H + jglob];
      float in_ = v[2] + bih[2 * H + jglob];
      float hr = v[3] + bhh[jglob];
      float hz = v[4] + bhh[H + jglob];
      float hn = v[5] + bhh[2 * H + jglob];
      float rr_ = sigmoidf_(ir + hr);
      float zz_ = sigmoidf_(iz + hz);
      float nn_ = tanhf(in_ + rr_ * hn);
      float hp = h_prev[(size_t)bglob * H + jglob];
      float ho = (1.f - zz_) * nn_ + zz_ * hp;
      h_out[(size_t)bglob * H + jglob] = ho;
      ushort_t hb, lb;
      split_bf16(ho, hb, lb);
      out_hi[(size_t)bglob * H + jglob] = hb;
      out_lo[(size_t)bglob * H + jglob] = lb;
    } else if (EPI == 1) {
      float vv = v[0] + bias[jglob];
      vv = fmaxf(vv, 0.f);
      ushort_t hb, lb;
      split_bf16(vv, hb, lb);
      out_hi[(size_t)bglob * split_pitch + jglob] = hb;
      out_lo[(size_t)bglob * split_pitch + jglob] = lb;
    } else {
      float vv = v[0] + bias[jglob];
      out_f32[(size_t)bglob * out_pitch + jglob] = vv;
      ushort_t hb, lb;
      split_bf16(vv, hb, lb);
      out_hi[(size_t)bglob * split_pitch + jglob] = hb;
      out_lo[(size_t)bglob * split_pitch + jglob] = lb;
    }
  }
  __syncthreads();
}

// ---------------- persistent kernel (8 independent group recurrences) ----------------

struct PParams {
  const ushort_t *ctxh, *ctxl;
  const ushort_t *wih0h, *whh0h;
  const ushort_t *wih1h, *whh1h;
  const ushort_t *w1h, *w2h;
  const float *bih0, *bhh0, *bih1, *bhh1, *bp1, *bp2;
  float *h0f0, *h0f1, *h1f0, *h1f1;
  ushort_t *h0hi0, *h0lo0, *h0hi1, *h0lo1;
  ushort_t *h1hi0, *h1lo0, *h1hi1, *h1lo1;
  ushort_t *h0Ahi, *h0Alo;
  ushort_t *phi, *plo, *yhi, *ylo;
  float* out;
  unsigned* bar;
  int T_in, n_pred, ctx_pitch;
};

__global__ __launch_bounds__(256, 1) void gru_persistent(PParams P) {
  __shared__ char smem[65536];
  const int tid = threadIdx.x;
  const int g = blockIdx.x & 7;      // group = batch rows [g*16,(g+1)*16); XCD under round-robin
  const int m = blockIdx.x >> 3;     // j-tile within group, 0..31

  float* h0f[2] = {P.h0f0, P.h0f1};
  float* h1f[2] = {P.h1f0, P.h1f1};
  ushort_t* h0hi[2] = {P.h0hi0, P.h0hi1};
  ushort_t* h0lo[2] = {P.h0lo0, P.h0lo1};
  ushort_t* h1hi[2] = {P.h1hi0, P.h1hi1};
  ushort_t* h1lo[2] = {P.h1lo0, P.h1lo1};

  int p0 = 0, p1 = 0;

  // -------- encoder chain 1: layer-0 for all t --------
  const ushort_t* e0ph = h0hi[0];
  const ushort_t* e0pl = h0lo[0];
  #pragma unroll 1
  for (int t = 0; t < P.T_in; ++t) {
    const int n0 = p0 ^ 1;
    ushort_t* oh = P.h0Ahi + (size_t)t * B * H;
    ushort_t* ol = P.h0Alo + (size_t)t * B * H;
    phase_mm<2, 3, 2, 0>(smem, tid, g, m,
        P.ctxh + (size_t)t * LATENT, P.ctxl + (size_t)t * LATENT, P.ctx_pitch, LATENT,
        P.wih0h,
        e0ph, e0pl, H, H, P.whh0h,
        P.bih0, P.bhh0, h0f[p0], h0f[n0], oh, ol, H,
        nullptr, nullptr, 0);
    group_barrier(P.bar, tid, g, m);
    e0ph = oh; e0pl = ol; p0 = n0;
  }

  // -------- encoder chain 2: layer-1 for all t --------
  #pragma unroll 1
  for (int t = 0; t < P.T_in; ++t) {
    const int n1 = p1 ^ 1;
    phase_mm<2, 3, 2, 0>(smem, tid, g, m,
        P.h0Ahi + (size_t)t * B * H, P.h0Alo + (size_t)t * B * H, H, H,
        P.wih1h,
        h1hi[p1], h1lo[p1], H, H, P.whh1h,
        P.bih1, P.bhh1, h1f[p1], h1f[n1], h1hi[n1], h1lo[n1], H,
        nullptr, nullptr, 0);
    group_barrier(P.bar, tid, g, m);
    p1 = n1;
  }

  // -------- decoder --------
  const ushort_t* d0ph = e0ph;
  const ushort_t* d0pl = e0pl;
  #pragma unroll 1
  for (int t = 0; t < P.n_pred; ++t) {
    const ushort_t *xh, *xl; int xpitch;
    if (t == 0) {
      xh = P.ctxh + (size_t)(P.T_in - 1) * LATENT;
      xl = P.ctxl + (size_t)(P.T_in - 1) * LATENT;
      xpitch = P.ctx_pitch;
    } else {
      xh = P.yhi; xl = P.ylo; xpitch = LATENT;
    }
    const int n0 = p0 ^ 1;
    phase_mm<2, 3, 2, 0>(smem, tid, g, m,
        xh, xl, xpitch, LATENT,
        P.wih0h,
        d0ph, d0pl, H, H, P.whh0h,
        P.bih0, P.bhh0, h0f[p0], h0f[n0], h0hi[n0], h0lo[n0], H,
        nullptr, nullptr, 0);
    group_barrier(P.bar, tid, g, m);
    d0ph = h0hi[n0]; d0pl = h0lo[n0];
    const int n1 = p1 ^ 1;
    phase_mm<2, 3, 2, 0>(smem, tid, g, m,
        h0hi[n0], h0lo[n0], H, H,
        P.wih1h,
        h1hi[p1], h1lo[p1], H, H, P.whh1h,
        P.bih1, P.bhh1, h1f[p1], h1f[n1], h1hi[n1], h1lo[n1], H,
        nullptr, nullptr, 0);
    group_barrier(P.bar, tid, g, m);
    // p = relu(h1 @ w1^T + bp1): N=1024 -> NJ=2
    phase_mm<2, 1, 1, 1>(smem, tid, g, m,
        h1hi[n1], h1lo[n1], H, H,
        P.w1h,
        nullptr, nullptr, 0, 0, nullptr,
        nullptr, nullptr, nullptr, nullptr, P.phi, P.plo, H,
        P.bp1, nullptr, 0);
    group_barrier(P.bar, tid, g, m);
    // y = p @ w2^T + bp2: N=512 -> NJ=1 (all 32 blocks x 16 cols)
    phase_mm<1, 1, 1, 2>(smem, tid, g, m,
        P.phi, P.plo, H, H,
        P.w2h,
        nullptr, nullptr, 0, 0, nullptr,
        nullptr, nullptr, nullptr, nullptr, P.yhi, P.ylo, LATENT,
        P.bp2, P.out + (size_t)t * LATENT, P.n_pred * LATENT);
    group_barrier(P.bar, tid, g, m);
    p0 = n0; p1 = n1;
  }
}

// ---------------- fp32 fallback (round-1, known-good) ----------------

__global__ __launch_bounds__(256) void gru_cell_kernel(
    const float* __restrict__ x, int xs, int Kih,
    const float* __restrict__ h_prev,
    const float* __restrict__ wih, const float* __restrict__ whh,
    const float* __restrict__ bih, const float* __restrict__ bhh,
    float* __restrict__ h_out)
{
  __shared__ float Xs[32][33];
  __shared__ float Ws[48][33];
  const int tid = threadIdx.x;
  const int b0 = blockIdx.x * 32;
  const int j0 = blockIdx.y * 16;
  const int bg = tid & 15;
  const int jj = tid >> 4;
  const int j = j0 + jj;
  float accA[2][3];
  float accB[2][3];
  #pragma unroll
  for (int g = 0; g < 3; ++g) {
    const float bi = bih[g * H + j];
    const float bh = bhh[g * H + j];
    accA[0][g] = bi; accA[1][g] = bi;
    accB[0][g] = bh; accB[1][g] = bh;
  }
  for (int k0 = 0; k0 < Kih; k0 += 32) {
    {
      const int rr = tid >> 3, c4 = (tid & 7) << 2;
      const float4 v = *reinterpret_cast<const float4*>(&x[(size_t)(b0 + rr) * xs + k0 + c4]);
      Xs[rr][c4 + 0] = v.x; Xs[rr][c4 + 1] = v.y; Xs[rr][c4 + 2] = v.z; Xs[rr][c4 + 3] = v.w;
    }
    for (int li = tid; li < 48 * 8; li += 256) {
      const int rr = li >> 3, c4 = (li & 7) << 2;
      const int g = rr >> 4, jr = rr & 15;
      const float4 v = *reinterpret_cast<const float4*>(&wih[(size_t)(g * H + j0 + jr) * Kih + k0 + c4]);
      Ws[rr][c4 + 0] = v.x; Ws[rr][c4 + 1] = v.y; Ws[rr][c4 + 2] = v.z; Ws[rr][c4 + 3] = v.w;
    }
    __syncthreads();
    #pragma unroll
    for (int k = 0; k < 32; ++k) {
      const float x0 = Xs[bg][k];
      const float x1 = Xs[bg + 16][k];
      #pragma unroll
      for (int g = 0; g < 3; ++g) {
        const float wv = Ws[g * 16 + jj][k];
        accA[0][g] = fmaf(x0, wv, accA[0][g]);
        accA[1][g] = fmaf(x1, wv, accA[1][g]);
      }
    }
    __syncthreads();
  }
  for (int k0 = 0; k0 < H; k0 += 32) {
    {
      const int rr = tid >> 3, c4 = (tid & 7) << 2;
      const float4 v = *reinterpret_cast<const float4*>(&h_prev[(size_t)(b0 + rr) * H + k0 + c4]);
      Xs[rr][c4 + 0] = v.x; Xs[rr][c4 + 1] = v.y; Xs[rr][c4 + 2] = v.z; Xs[rr][c4 + 3] = v.w;
    }
    for (int li = tid; li < 48 * 8; li += 256) {
      const int rr = li >> 3, c4 = (li & 7) << 2;
      const int g = rr >> 4, jr = rr & 15;
      const float4 v = *reinterpret_cast<const float4*>(&whh[(size_t)(g * H + j0 + jr) * H + k0 + c4]);
      Ws[rr][c4 + 0] = v.x; Ws[rr][c4 + 1] = v.y; Ws[rr][c4 + 2] = v.z; Ws[rr][c4 + 3] = v.w;
    }
    __syncthreads();
    #pragma unroll
    for (int k = 0; k < 32; ++k) {
      const float h0v = Xs[bg][k];
      const float h1v = Xs[bg + 16][k];
      #pragma unroll
      for (int g = 0; g < 3; ++g) {
        const float wv = Ws[g * 16 + jj][k];
        accB[0][g] = fmaf(h0v, wv, accB[0][g]);
        accB[1][g] = fmaf(h1v, wv, accB[1][g]);
      }
    }
    __syncthreads();
  }
  #pragma unroll
  for (int i = 0; i < 2; ++i) {
    const int b = b0 + bg + i * 16;
    const float hp = h_prev[(size_t)b * H + j];
    const float r = sigmoidf_(accA[i][0] + accB[i][0]);
    const float z = sigmoidf_(accA[i][1] + accB[i][1]);
    const float n = tanhf(accA[i][2] + r * accB[i][2]);
    h_out[(size_t)b * H + j] = (1.0f - z) * n + z * hp;
  }
}

__global__ __launch_bounds__(256) void gemm_bias_kernel(
    const float* __restrict__ X, int xs, int K,
    const float* __restrict__ W, const float* __restrict__ bias,
    float* __restrict__ out1, int o1s,
    float* __restrict__ out2, int o2s,
    int relu)
{
  __shared__ float Xs[32][33];
  __shared__ float Ws[16][33];
  const int tid = threadIdx.x;
  const int b0 = blockIdx.x * 32;
  const int n0 = blockIdx.y * 16;
  const int bg = tid & 15;
  const int nn = tid >> 4;
  const int n = n0 + nn;
  float acc0 = bias[n];
  float acc1 = acc0;
  for (int k0 = 0; k0 < K; k0 += 32) {
    {
      const int rr = tid >> 3, c4 = (tid & 7) << 2;
      const float4 v = *reinterpret_cast<const float4*>(&X[(size_t)(b0 + rr) * xs + k0 + c4]);
      Xs[rr][c4 + 0] = v.x; Xs[rr][c4 + 1] = v.y; Xs[rr][c4 + 2] = v.z; Xs[rr][c4 + 3] = v.w;
    }
    if (tid < 128) {
      const int rr = tid >> 3, c4 = (tid & 7) << 2;
      const float4 v = *reinterpret_cast<const float4*>(&W[(size_t)(n0 + rr) * K + k0 + c4]);
      Ws[rr][c4 + 0] = v.x; Ws[rr][c4 + 1] = v.y; Ws[rr][c4 + 2] = v.z; Ws[rr][c4 + 3] = v.w;
    }
    __syncthreads();
    #pragma unroll
    for (int k = 0; k < 32; ++k) {
      const float wv = Ws[nn][k];
      acc0 = fmaf(Xs[bg][k], wv, acc0);
      acc1 = fmaf(Xs[bg + 16][k], wv, acc1);
    }
    __syncthreads();
  }
  if (relu) { acc0 = fmaxf(acc0, 0.0f); acc1 = fmaxf(acc1, 0.0f); }
  const int ba = b0 + bg, bb = b0 + bg + 16;
  out1[(size_t)ba * o1s + n] = acc0;
  out1[(size_t)bb * o1s + n] = acc1;
  if (out2 != nullptr) {
    out2[(size_t)ba * o2s + n] = acc0;
    out2[(size_t)bb * o2s + n] = acc1;
  }
}

// ---------------- host launch ----------------

extern "C" void kernel_launch(void* const* d_in, const int* in_sizes, int n_in,
                              void* d_out, int out_size, void* d_ws, size_t ws_size,
                              hipStream_t stream) {
  (void)n_in;
  const float* ctx  = (const float*)d_in[0];
  const float* wih0 = (const float*)d_in[1];
  const float* whh0 = (const float*)d_in[2];
  const float* bih0 = (const float*)d_in[3];
  const float* bhh0 = (const float*)d_in[4];
  const float* wih1 = (const float*)d_in[5];
  const float* whh1 = (const float*)d_in[6];
  const float* bih1 = (const float*)d_in[7];
  const float* bhh1 = (const float*)d_in[8];
  const float* w1   = (const float*)d_in[9];
  const float* bp1  = (const float*)d_in[10];
  const float* w2   = (const float*)d_in[11];
  const float* bp2  = (const float*)d_in[12];

  const int T_in   = in_sizes[0] / (B * LATENT);
  const int n_pred = out_size / (B * LATENT);
  float* out = (float*)d_out;

  // ---- ws layout ----
  size_t cur = 0;
  auto alloc = [&](size_t bytes) -> void* {
    void* p = (char*)d_ws + cur;
    cur += (bytes + 255) & ~(size_t)255;
    return p;
  };
  const int E_wih0 = 3 * H * LATENT, E_whh0 = 3 * H * H;
  const int E_wih1 = 3 * H * H, E_whh1 = 3 * H * H;
  const int E_w1 = H * H, E_w2 = LATENT * H;
  const int E_ctx = in_sizes[0];

  ushort_t* wih0h = (ushort_t*)alloc(E_wih0 * 2);
  ushort_t* whh0h = (ushort_t*)alloc(E_whh0 * 2);
  ushort_t* wih1h = (ushort_t*)alloc(E_wih1 * 2);
  ushort_t* whh1h = (ushort_t*)alloc(E_whh1 * 2);
  ushort_t* w1h   = (ushort_t*)alloc(E_w1 * 2);
  ushort_t* w2h   = (ushort_t*)alloc(E_w2 * 2);
  ushort_t* ctxh  = (ushort_t*)alloc((size_t)E_ctx * 2);
  ushort_t* ctxl  = (ushort_t*)alloc((size_t)E_ctx * 2);
  ushort_t* h0Ahi = (ushort_t*)alloc((size_t)T_in * B * H * 2);
  ushort_t* h0Alo = (ushort_t*)alloc((size_t)T_in * B * H * 2);
  size_t zero_start = cur;
  float* h0f[2]; float* h1f[2];
  ushort_t* h0hi[2]; ushort_t* h0lo[2]; ushort_t* h1hi[2]; ushort_t* h1lo[2];
  h0f[0] = (float*)alloc(B * H * 4); h0f[1] = (float*)alloc(B * H * 4);
  h1f[0] = (float*)alloc(B * H * 4); h1f[1] = (float*)alloc(B * H * 4);
  h0hi[0] = (ushort_t*)alloc(B * H * 2); h0lo[0] = (ushort_t*)alloc(B * H * 2);
  h0hi[1] = (ushort_t*)alloc(B * H * 2); h0lo[1] = (ushort_t*)alloc(B * H * 2);
  h1hi[0] = (ushort_t*)alloc(B * H * 2); h1lo[0] = (ushort_t*)alloc(B * H * 2);
  h1hi[1] = (ushort_t*)alloc(B * H * 2); h1lo[1] = (ushort_t*)alloc(B * H * 2);
  ushort_t* phi = (ushort_t*)alloc(B * H * 2); ushort_t* plo = (ushort_t*)alloc(B * H * 2);
  ushort_t* yhi = (ushort_t*)alloc(B * LATENT * 2); ushort_t* ylo = (ushort_t*)alloc(B * LATENT * 2);
  unsigned* bar = (unsigned*)alloc(16384);
  size_t zero_bytes = cur - zero_start;
  size_t required = cur;

  if (ws_size >= required) {
    // ---------- MFMA 2-term split-bf16 grouped persistent path ----------
    auto splitA = [&](const float* s, ushort_t* hi, ushort_t* lo, int n) {
      int blocks = (n + 255) / 256; if (blocks > 2048) blocks = 2048;
      split_kernel<<<blocks, 256, 0, stream>>>(s, hi, lo, n);
    };
    auto splitW = [&](const float* s, ushort_t* hi, int n) {
      int blocks = (n + 255) / 256; if (blocks > 2048) blocks = 2048;
      split_hi_kernel<<<blocks, 256, 0, stream>>>(s, hi, n);
    };
    splitW(wih0, wih0h, E_wih0);
    splitW(whh0, whh0h, E_whh0);
    splitW(wih1, wih1h, E_wih1);
    splitW(whh1, whh1h, E_whh1);
    splitW(w1, w1h, E_w1);
    splitW(w2, w2h, E_w2);
    splitA(ctx, ctxh, ctxl, E_ctx);
    {
      int n4 = (int)(zero_bytes / 16);
      zero4_kernel<<<2048, 256, 0, stream>>>((float4*)((char*)d_ws + zero_start), n4);
    }

    PParams P;
    P.ctxh = ctxh; P.ctxl = ctxl;
    P.wih0h = wih0h; P.whh0h = whh0h;
    P.wih1h = wih1h; P.whh1h = whh1h;
    P.w1h = w1h; P.w2h = w2h;
    P.bih0 = bih0; P.bhh0 = bhh0; P.bih1 = bih1; P.bhh1 = bhh1;
    P.bp1 = bp1; P.bp2 = bp2;
    P.h0f0 = h0f[0]; P.h0f1 = h0f[1]; P.h1f0 = h1f[0]; P.h1f1 = h1f[1];
    P.h0hi0 = h0hi[0]; P.h0lo0 = h0lo[0]; P.h0hi1 = h0hi[1]; P.h0lo1 = h0lo[1];
    P.h1hi0 = h1hi[0]; P.h1lo0 = h1lo[0]; P.h1hi1 = h1hi[1]; P.h1lo1 = h1lo[1];
    P.h0Ahi = h0Ahi; P.h0Alo = h0Alo;
    P.phi = phi; P.plo = plo; P.yhi = yhi; P.ylo = ylo;
    P.out = out; P.bar = bar;
    P.T_in = T_in; P.n_pred = n_pred; P.ctx_pitch = T_in * LATENT;

    gru_persistent<<<256, 256, 0, stream>>>(P);
    return;
  }

  // ---------- fp32 fallback path (round-1) ----------
  float* ws = (float*)d_ws;
  float* h0a = ws;
  float* h0b = h0a + (size_t)B * H;
  float* h1a = h0b + (size_t)B * H;
  float* h1b = h1a + (size_t)B * H;
  float* p   = h1b + (size_t)B * H;
  {
    int n4 = (4 * B * H) / 4;
    zero4_kernel<<<256, 256, 0, stream>>>((float4*)h0a, n4);
  }
  float* y = p + (size_t)B * H;
  float* h0p = h0a; float* h0n = h0b;
  float* h1p = h1a; float* h1n = h1b;
  const dim3 cgrid(4, 64);
  for (int t = 0; t < T_in; ++t) {
    const float* x = ctx + (size_t)t * LATENT;
    gru_cell_kernel<<<cgrid, 256, 0, stream>>>(x, T_in * LATENT, LATENT,
                                               h0p, wih0, whh0, bih0, bhh0, h0n);
    gru_cell_kernel<<<cgrid, 256, 0, stream>>>(h0n, H, H,
                                               h1p, wih1, whh1, bih1, bhh1, h1n);
    float* tmp;
    tmp = h0p; h0p = h0n; h0n = tmp;
    tmp = h1p; h1p = h1n; h1n = tmp;
  }
  for (int t = 0; t < n_pred; ++t) {
    const float* x; int xstride;
    if (t == 0) { x = ctx + (size_t)(T_in - 1) * LATENT; xstride = T_in * LATENT; }
    else        { x = y; xstride = LATENT; }
    gru_cell_kernel<<<cgrid, 256, 0, stream>>>(x, xstride, LATENT,
                                               h0p, wih0, whh0, bih0, bhh0, h0n);
    gru_cell_kernel<<<cgrid, 256, 0, stream>>>(h0n, H, H,
                                               h1p, wih1, whh1, bih1, bhh1, h1n);
    gemm_bias_kernel<<<dim3(4, H / 16), 256, 0, stream>>>(h1n, H, H, w1, bp1,
                                                          p, H, nullptr, 0, 1);
    gemm_bias_kernel<<<dim3(4, LATENT / 16), 256, 0, stream>>>(p, H, H, w2, bp2,
                                                               y, LATENT,
                                                               out + (size_t)t * LATENT,
                                                               n_pred * LATENT, 0);
    float* tmp;
    tmp = h0p; h0p = h0n; h0n = tmp;
    tmp = h1p; h1p = h1n; h1n = tmp;
  }
}

// Round 14
// 6677.170 us; speedup vs baseline: 1.2208x; 1.2208x over previous
//
#include <hip/hip_runtime.h>
#include <math.h>

#define B 128
#define LATENT 512
#define H 1024
#define BH (B * H)

typedef unsigned short ushort_t;
typedef unsigned int uint_t;
typedef __bf16 bf16x8 __attribute__((ext_vector_type(8)));
typedef float f32x4 __attribute__((ext_vector_type(4)));

// ---------------- common small kernels ----------------

__global__ __launch_bounds__(256) void zero4_kernel(float4* __restrict__ p, int n4) {
  int i = blockIdx.x * blockDim.x + threadIdx.x;
  int stride = gridDim.x * blockDim.x;
  float4 z = {0.f, 0.f, 0.f, 0.f};
  for (; i < n4; i += stride) p[i] = z;
}

__device__ __forceinline__ void split_bf16(float f, ushort_t& h, ushort_t& l) {
  uint_t u = __float_as_uint(f);
  uint_t hb = (u + 0x7FFFu + ((u >> 16) & 1u)) >> 16;
  float fh = __uint_as_float(hb << 16);
  float r = f - fh;
  uint_t v = __float_as_uint(r);
  uint_t lb = (v + 0x7FFFu + ((v >> 16) & 1u)) >> 16;
  h = (ushort_t)hb; l = (ushort_t)lb;
}

__global__ __launch_bounds__(256) void split_kernel(const float* __restrict__ src,
                                                    ushort_t* __restrict__ hi,
                                                    ushort_t* __restrict__ lo, int n) {
  int i = blockIdx.x * blockDim.x + threadIdx.x;
  int stride = gridDim.x * blockDim.x;
  for (; i < n; i += stride) {
    ushort_t h, l;
    split_bf16(src[i], h, l);
    hi[i] = h; lo[i] = l;
  }
}

__global__ __launch_bounds__(256) void split_hi_kernel(const float* __restrict__ src,
                                                       ushort_t* __restrict__ hi, int n) {
  int i = blockIdx.x * blockDim.x + threadIdx.x;
  int stride = gridDim.x * blockDim.x;
  for (; i < n; i += stride) {
    uint_t u = __float_as_uint(src[i]);
    hi[i] = (ushort_t)((u + 0x7FFFu + ((u >> 16) & 1u)) >> 16);
  }
}

// wf = wih0 @ w2  (fp32 GEMM, split hi/lo).  [3H x 512] @ [512 x H] -> [3H x H]
__global__ __launch_bounds__(256) void wf_kernel(const float* __restrict__ wih0,
                                                 const float* __restrict__ w2,
                                                 ushort_t* __restrict__ wfh,
                                                 ushort_t* __restrict__ wfl) {
  __shared__ float As[32][33];
  __shared__ float Bs[32][33];
  const int i0 = blockIdx.x * 32;
  const int k0 = blockIdx.y * 32;
  const int tid = threadIdx.x;
  const int r = tid >> 3, c4 = (tid & 7) << 2;
  float acc[4] = {0.f, 0.f, 0.f, 0.f};
  for (int m0 = 0; m0 < LATENT; m0 += 32) {
    {
      const float4 v = *reinterpret_cast<const float4*>(&wih0[(size_t)(i0 + r) * LATENT + m0 + c4]);
      As[r][c4] = v.x; As[r][c4 + 1] = v.y; As[r][c4 + 2] = v.z; As[r][c4 + 3] = v.w;
      const float4 w = *reinterpret_cast<const float4*>(&w2[(size_t)(m0 + r) * H + k0 + c4]);
      Bs[r][c4] = w.x; Bs[r][c4 + 1] = w.y; Bs[r][c4 + 2] = w.z; Bs[r][c4 + 3] = w.w;
    }
    __syncthreads();
    #pragma unroll
    for (int mm = 0; mm < 32; ++mm) {
      const float a = As[r][mm];
      #pragma unroll
      for (int x = 0; x < 4; ++x) acc[x] = fmaf(a, Bs[mm][c4 + x], acc[x]);
    }
    __syncthreads();
  }
  #pragma unroll
  for (int x = 0; x < 4; ++x) {
    ushort_t h, l;
    split_bf16(acc[x], h, l);
    const size_t o = (size_t)(i0 + r) * H + k0 + c4 + x;
    wfh[o] = h; wfl[o] = l;
  }
}

// bf0[g] = bih0[g] + dot(wih0[g,:], bp2)  -- bias folding for the fused gi path
__global__ __launch_bounds__(256) void bias_fuse_kernel(const float* __restrict__ wih0,
                                                        const float* __restrict__ bp2,
                                                        const float* __restrict__ bih0,
                                                        float* __restrict__ bf0) {
  int g = blockIdx.x * blockDim.x + threadIdx.x;
  if (g < 3 * H) {
    float s = bih0[g];
    const float* row = wih0 + (size_t)g * LATENT;
    #pragma unroll 4
    for (int l = 0; l < LATENT; ++l) s = fmaf(row[l], bp2[l], s);
    bf0[g] = s;
  }
}

__device__ __forceinline__ float sigmoidf_(float v) { return 1.0f / (1.0f + expf(-v)); }

// ---------------- hierarchical grid barrier (round-6 form, known good) ----------------
__device__ __forceinline__ void grid_barrier(unsigned* bar, int tid, int bid) {
  __syncthreads();
  if (tid == 0) {
    const int g = bid & 7;
    unsigned* arr    = bar + (g << 6);
    unsigned* rel    = bar + 1024 + (g << 6);
    unsigned* master = bar + 2048;
    unsigned gen = __hip_atomic_load(rel, __ATOMIC_RELAXED, __HIP_MEMORY_SCOPE_AGENT);
    unsigned a = __hip_atomic_fetch_add(arr, 1u, __ATOMIC_ACQ_REL, __HIP_MEMORY_SCOPE_AGENT);
    if (a == 31u) {
      __hip_atomic_store(arr, 0u, __ATOMIC_RELAXED, __HIP_MEMORY_SCOPE_AGENT);
      unsigned m = __hip_atomic_fetch_add(master, 1u, __ATOMIC_ACQ_REL, __HIP_MEMORY_SCOPE_AGENT);
      if (m == 7u) {
        __hip_atomic_store(master, 0u, __ATOMIC_RELAXED, __HIP_MEMORY_SCOPE_AGENT);
        #pragma unroll
        for (int i = 0; i < 8; ++i)
          __hip_atomic_fetch_add(bar + 1024 + (i << 6), 1u, __ATOMIC_ACQ_REL, __HIP_MEMORY_SCOPE_AGENT);
      }
    }
    while (__hip_atomic_load(rel, __ATOMIC_RELAXED, __HIP_MEMORY_SCOPE_AGENT) == gen)
      __builtin_amdgcn_s_sleep(1);
    (void)__hip_atomic_load(rel, __ATOMIC_ACQUIRE, __HIP_MEMORY_SCOPE_AGENT);
  }
  __syncthreads();
}

// ---------------- one GEMM phase: 32 rows x NJ*16 cols x NG gates ----------------
// Numerics (as r11): acc = xh@wh + xl@wh; if WLO (fused gi via wf): + xh@wl.
// EPI: 0=GRU gates, 1=relu+bias->split, 3=bias->scattered f32 (final ys).
template <int NJ, int NG, int PH, int EPI, bool WLO>
__device__ __forceinline__ void phase_mm(
    char* smem, const int tid, const int Mb, const int jb, const bool active,
    const ushort_t* aAh, const ushort_t* aAl, int aApitch, int K1,
    const ushort_t* wAh, const ushort_t* wAl,
    const ushort_t* aBh, const ushort_t* aBl, int aBpitch, int K2,
    const ushort_t* wBh,
    const float* bih, const float* bhh,
    const float* h_prev, float* h_out,
    ushort_t* out_hi, ushort_t* out_lo, int split_pitch,
    const float* bias, float* out_f32)
{
  if (!active) return;
  constexpr int NW = NJ * NG;
  constexpr int NSLOTA = 4 + NW * (WLO ? 2 : 1);
  constexpr int NSLOTB = 4 + NW;
  constexpr int BUFB = NSLOTA * 4096;
  constexpr int NPG = PH * NW;
  constexpr int CW = NJ * 16;

  const int b0 = Mb * 32;
  const int j0 = jb * CW;
  const int NC1 = K1 >> 7;
  const int NC2 = (PH == 2) ? (K2 >> 7) : 0;
  const int NC = NC1 + NC2;

  const char* g[NSLOTA];
  auto build = [&](const ushort_t* ah, const ushort_t* al, int apitch,
                   const ushort_t* wh, const ushort_t* wl, int K) {
    const int rowt = tid >> 4;
    const int cp = tid & 15;
    const int cc = cp ^ rowt;
    #pragma unroll
    for (int u = 0; u < NSLOTA; ++u) {
      const ushort_t* basep; size_t off;
      if (u < 2)      { basep = ah; off = (size_t)(b0 + u * 16 + rowt) * apitch + cc * 8; }
      else if (u < 4) { basep = al; off = (size_t)(b0 + (u - 2) * 16 + rowt) * apitch + cc * 8; }
      else if (u < 4 + NW) {
        const int w = u - 4, jt = w % NJ, gate = w / NJ;
        const int wrow = (NG == 3) ? (gate * H + j0 + jt * 16 + rowt) : (j0 + jt * 16 + rowt);
        basep = wh; off = (size_t)wrow * K + cc * 8;
      } else {
        const int w = u - 4 - NW, jt = w % NJ, gate = w / NJ;
        const int wrow = (NG == 3) ? (gate * H + j0 + jt * 16 + rowt) : (j0 + jt * 16 + rowt);
        basep = (wl != nullptr) ? wl : wh; off = (size_t)wrow * K + cc * 8;
      }
      g[u] = (const char*)(basep + off);
    }
  };

  // fragment read offsets
  const int s = tid >> 6;
  const int q = (tid >> 4) & 3;
  const int r = tid & 15;
  const int gs = (((4 * s + q) ^ r) << 4);
  const int offA00 = r * 256 + gs;
  const int offA01 = 4096 + r * 256 + gs;
  const int offA10 = 8192 + r * 256 + gs;
  const int offA11 = 12288 + r * 256 + gs;
  int offWh[NW];
  int offWl[NW];
  #pragma unroll
  for (int w = 0; w < NW; ++w) {
    offWh[w] = (4 + w) * 4096 + r * 256 + gs;
    offWl[w] = (4 + NW + w) * 4096 + r * 256 + gs;
  }

  f32x4 accA[NJ][NG][2];
  f32x4 accB[NJ][NG][2];
  #pragma unroll
  for (int jt = 0; jt < NJ; ++jt)
    #pragma unroll
    for (int gg = 0; gg < NG; ++gg)
      #pragma unroll
      for (int mf = 0; mf < 2; ++mf) {
        accA[jt][gg][mf] = (f32x4){0.f, 0.f, 0.f, 0.f};
        accB[jt][gg][mf] = (f32x4){0.f, 0.f, 0.f, 0.f};
      }

  const unsigned wofs = (unsigned)(tid >> 6) * 1024;
  auto issue = [&](int bsel, int koff, int nslot) {
    #pragma unroll
    for (int u = 0; u < NSLOTA; ++u) {
      if (u < nslot) {
        __builtin_amdgcn_global_load_lds(
            (const __attribute__((address_space(1))) void*)(g[u] + koff),
            (__attribute__((address_space(3))) void*)(smem + bsel * BUFB + u * 4096 + wofs),
            16, 0, 0);
      }
    }
  };

  auto computeA = [&](int bsel) {
    const char* base = smem + bsel * BUFB;
    bf16x8 ah0 = *(const bf16x8*)(base + offA00);
    bf16x8 ah1 = *(const bf16x8*)(base + offA01);
    bf16x8 al0 = *(const bf16x8*)(base + offA10);
    bf16x8 al1 = *(const bf16x8*)(base + offA11);
    #pragma unroll
    for (int gg = 0; gg < NG; ++gg)
      #pragma unroll
      for (int jt = 0; jt < NJ; ++jt) {
        const int w = gg * NJ + jt;
        bf16x8 wh = *(const bf16x8*)(base + offWh[w]);
        accA[jt][gg][0] = __builtin_amdgcn_mfma_f32_16x16x32_bf16(ah0, wh, accA[jt][gg][0], 0, 0, 0);
        if (WLO) {
          bf16x8 wl = *(const bf16x8*)(base + offWl[w]);
          accA[jt][gg][0] = __builtin_amdgcn_mfma_f32_16x16x32_bf16(ah0, wl, accA[jt][gg][0], 0, 0, 0);
          accA[jt][gg][1] = __builtin_amdgcn_mfma_f32_16x16x32_bf16(ah1, wl, accA[jt][gg][1], 0, 0, 0);
        }
        accA[jt][gg][0] = __builtin_amdgcn_mfma_f32_16x16x32_bf16(al0, wh, accA[jt][gg][0], 0, 0, 0);
        accA[jt][gg][1] = __builtin_amdgcn_mfma_f32_16x16x32_bf16(ah1, wh, accA[jt][gg][1], 0, 0, 0);
        accA[jt][gg][1] = __builtin_amdgcn_mfma_f32_16x16x32_bf16(al1, wh, accA[jt][gg][1], 0, 0, 0);
      }
  };
  auto computeB = [&](int bsel) {
    const char* base = smem + bsel * BUFB;
    bf16x8 ah0 = *(const bf16x8*)(base + offA00);
    bf16x8 ah1 = *(const bf16x8*)(base + offA01);
    bf16x8 al0 = *(const bf16x8*)(base + offA10);
    bf16x8 al1 = *(const bf16x8*)(base + offA11);
    #pragma unroll
    for (int gg = 0; gg < NG; ++gg)
      #pragma unroll
      for (int jt = 0; jt < NJ; ++jt) {
        const int w = gg * NJ + jt;
        bf16x8 wh = *(const bf16x8*)(base + offWh[w]);
        accB[jt][gg][0] = __builtin_amdgcn_mfma_f32_16x16x32_bf16(ah0, wh, accB[jt][gg][0], 0, 0, 0);
        accB[jt][gg][0] = __builtin_amdgcn_mfma_f32_16x16x32_bf16(al0, wh, accB[jt][gg][0], 0, 0, 0);
        accB[jt][gg][1] = __builtin_amdgcn_mfma_f32_16x16x32_bf16(ah1, wh, accB[jt][gg][1], 0, 0, 0);
        accB[jt][gg][1] = __builtin_amdgcn_mfma_f32_16x16x32_bf16(al1, wh, accB[jt][gg][1], 0, 0, 0);
      }
  };

  // prologue
  build(aAh, aAl, aApitch, wAh, wAl, K1);
  issue(0, 0, NSLOTA);

  #pragma unroll 1
  for (int c = 0; c < NC; ++c) {
    __syncthreads();
    if (c + 1 < NC) {
      if (PH == 2 && c + 1 == NC1) {
        build(aBh, aBl, aBpitch, wBh, nullptr, K2);
        issue((c + 1) & 1, 0, NSLOTB);
      } else {
        const bool isB = (PH == 2) && (c + 1 >= NC1);
        const int koff = (isB ? (c + 1 - NC1) : (c + 1)) * 256;
        issue((c + 1) & 1, koff, isB ? NSLOTB : NSLOTA);
      }
    }
    if (PH == 1 || c < NC1) computeA(c & 1);
    else                    computeB(c & 1);
  }
  __syncthreads();

  // ---- cross-wave reduce (alias smem) ----
  const int lane = tid & 63;
  #pragma unroll
  for (int gg = 0; gg < NG; ++gg)
    #pragma unroll
    for (int jt = 0; jt < NJ; ++jt)
      #pragma unroll
      for (int mf = 0; mf < 2; ++mf) {
        const int w = gg * NJ + jt;
        *(f32x4*)(smem + (size_t)(((s * NPG + w) * 2 + mf) * 64 + lane) * 16) = accA[jt][gg][mf];
        if (PH == 2)
          *(f32x4*)(smem + (size_t)(((s * NPG + NW + w) * 2 + mf) * 64 + lane) * 16) = accB[jt][gg][mf];
      }
  __syncthreads();

  for (int o = tid; o < 32 * CW; o += 256) {
    const int row = o / CW, c = o % CW;
    const int jt = c >> 4, cr = c & 15;
    const int mf = row >> 4, br = row & 15, qq = br >> 2, rg = br & 3;
    const int ln = cr + qq * 16;
    float v[PH * NG];
    #pragma unroll
    for (int pg = 0; pg < PH * NG; ++pg) {
      const int w = (pg < NG) ? (pg * NJ + jt) : (NW + (pg - NG) * NJ + jt);
      float sum = 0.f;
      #pragma unroll
      for (int ss = 0; ss < 4; ++ss)
        sum += *(const float*)(smem + (size_t)(((ss * NPG + w) * 2 + mf) * 64 + ln) * 16 + rg * 4);
      v[pg] = sum;
    }
    const int bglob = b0 + row, jglob = j0 + c;
    if (EPI == 0) {
      float ir = v[0] + bih[jglob];
      float iz = v[1] + bih[H + jglob];
      float in_ = v[2] + bih[2 * H + jglob];
      float hr = v[3] + bhh[jglob];
      float hz = v[4] + bhh[H + jglob];
      float hn = v[5] + bhh[2 * H + jglob];
      float rr_ = sigmoidf_(ir + hr);
      float zz_ = sigmoidf_(iz + hz);
      float nn_ = tanhf(in_ + rr_ * hn);
      float hp = h_prev[(size_t)bglob * H + jglob];
      float ho = (1.f - zz_) * nn_ + zz_ * hp;
      h_out[(size_t)bglob * H + jglob] = ho;
      ushort_t hb, lb;
      split_bf16(ho, hb, lb);
      out_hi[(size_t)bglob * H + jglob] = hb;
      out_lo[(size_t)bglob * H + jglob] = lb;
    } else if (EPI == 1) {
      float vv = v[0] + bias[jglob];
      vv = fmaxf(vv, 0.f);
      ushort_t hb, lb;
      split_bf16(vv, hb, lb);
      out_hi[(size_t)bglob * split_pitch + jglob] = hb;
      out_lo[(size_t)bglob * split_pitch + jglob] = lb;
    } else {
      // EPI==3: final ys write: row R = t*B + b -> out[b][t][jglob]
      float vv = v[0] + bias[jglob];
      const int tt = bglob >> 7, bb2 = bglob & 127;
      out_f32[((size_t)bb2 * split_pitch + tt) * LATENT + jglob] = vv;
    }
  }
  __syncthreads();
}

// ---------------- persistent kernel: 65 enc + 192 dec phases ----------------

struct PParams {
  const ushort_t *ctxh, *ctxl;
  const ushort_t *wih0h, *whh0h;
  const ushort_t *wih1h, *whh1h;
  const ushort_t *w1h;
  const ushort_t *wfh, *wfl;
  const float *bih0, *bhh0, *bih1, *bhh1, *bp1;
  const float *bf0;             // bih0 + wih0 @ bp2 (fused-gi bias)
  float *h0f0, *h0f1, *h1f0, *h1f1;
  ushort_t *h0hi0, *h0lo0, *h0hi1, *h0lo1;
  ushort_t *h1hi0, *h1lo0, *h1hi1, *h1lo1;
  ushort_t *h0Ahi, *h0Alo;      // [T_in][B][H]; aliased as pA in decoder
  unsigned* bar;
  int T_in, n_pred, ctx_pitch;
};

__global__ __launch_bounds__(256, 1) void gru_persistent(PParams P) {
  __shared__ char smem[98304];
  const int tid = threadIdx.x;
  const int bid = blockIdx.x;

  float* h0f[2] = {P.h0f0, P.h0f1};
  float* h1f[2] = {P.h1f0, P.h1f1};
  ushort_t* h0hi[2] = {P.h0hi0, P.h0hi1};
  ushort_t* h0lo[2] = {P.h0lo0, P.h0lo1};
  ushort_t* h1hi[2] = {P.h1hi0, P.h1hi1};
  ushort_t* h1lo[2] = {P.h1lo0, P.h1lo1};

  int p0 = 0, p1 = 0;

  // -------- pipelined encoder: phase p does L0[p] (blocks 0-127) || L1[p-1] (128-255) --------
  const int idx = (bid < 128) ? bid : (bid - 128);
  const int eMb = idx & 3;
  const int ejb = idx >> 2;   // 0..31, NJ=2 -> 32 cols
  #pragma unroll 1
  for (int p = 0; p <= P.T_in; ++p) {
    const int n0 = p0 ^ 1, n1 = p1 ^ 1;
    if (bid < 128) {
      if (p < P.T_in) {
        const int t = p;
        phase_mm<2, 3, 2, 0, false>(smem, tid, eMb, ejb, true,
            P.ctxh + (size_t)t * LATENT, P.ctxl + (size_t)t * LATENT, P.ctx_pitch, LATENT,
            P.wih0h, nullptr,
            (t == 0) ? P.h0hi0 : P.h0Ahi + (size_t)(t - 1) * BH,
            (t == 0) ? P.h0lo0 : P.h0Alo + (size_t)(t - 1) * BH, H, H, P.whh0h,
            P.bih0, P.bhh0, h0f[p0], h0f[n0],
            P.h0Ahi + (size_t)t * BH, P.h0Alo + (size_t)t * BH, H, nullptr, nullptr);
      }
    } else {
      if (p >= 1) {
        const int t = p - 1;
        phase_mm<2, 3, 2, 0, false>(smem, tid, eMb, ejb, true,
            P.h0Ahi + (size_t)t * BH, P.h0Alo + (size_t)t * BH, H, H,
            P.wih1h, nullptr,
            h1hi[p1], h1lo[p1], H, H, P.whh1h,
            P.bih1, P.bhh1, h1f[p1], h1f[n1],
            h1hi[n1], h1lo[n1], H, nullptr, nullptr);
      }
    }
    grid_barrier(P.bar, tid, bid);
    if (p < P.T_in) p0 = n0;
    if (p >= 1) p1 = n1;
  }

  // -------- decoder: 3 phases/step {D0 (fused gi via wf), D1, DP} --------
  const int dMb = bid & 3;
  const int djb = bid >> 2;   // 0..63
  const ushort_t* d0ph = P.h0Ahi + (size_t)(P.T_in - 1) * BH;
  const ushort_t* d0pl = P.h0Alo + (size_t)(P.T_in - 1) * BH;
  ushort_t* pAh = P.h0Ahi;    // alias: p[t] storage (h0A dead after t=0's D0)
  ushort_t* pAl = P.h0Alo;
  #pragma unroll 1
  for (int t = 0; t < P.n_pred; ++t) {
    const int n0 = p0 ^ 1;
    if (t == 0) {
      phase_mm<1, 3, 2, 0, false>(smem, tid, dMb, djb, true,
          P.ctxh + (size_t)(P.T_in - 1) * LATENT, P.ctxl + (size_t)(P.T_in - 1) * LATENT,
          P.ctx_pitch, LATENT,
          P.wih0h, nullptr,
          d0ph, d0pl, H, H, P.whh0h,
          P.bih0, P.bhh0, h0f[p0], h0f[n0], h0hi[n0], h0lo[n0], H, nullptr, nullptr);
    } else {
      phase_mm<1, 3, 2, 0, true>(smem, tid, dMb, djb, true,
          pAh + (size_t)(t - 1) * BH, pAl + (size_t)(t - 1) * BH, H, H,
          P.wfh, P.wfl,
          d0ph, d0pl, H, H, P.whh0h,
          P.bf0, P.bhh0, h0f[p0], h0f[n0], h0hi[n0], h0lo[n0], H, nullptr, nullptr);
    }
    grid_barrier(P.bar, tid, bid);
    d0ph = h0hi[n0]; d0pl = h0lo[n0];
    const int n1 = p1 ^ 1;
    phase_mm<1, 3, 2, 0, false>(smem, tid, dMb, djb, true,
        h0hi[n0], h0lo[n0], H, H,
        P.wih1h, nullptr,
        h1hi[p1], h1lo[p1], H, H, P.whh1h,
        P.bih1, P.bhh1, h1f[p1], h1f[n1], h1hi[n1], h1lo[n1], H, nullptr, nullptr);
    grid_barrier(P.bar, tid, bid);
    // p[t] = relu(h1 @ w1^T + bp1)
    phase_mm<1, 1, 1, 1, false>(smem, tid, dMb, djb, true,
        h1hi[n1], h1lo[n1], H, H,
        P.w1h, nullptr,
        nullptr, nullptr, 0, 0, nullptr,
        nullptr, nullptr, nullptr, nullptr,
        pAh + (size_t)t * BH, pAl + (size_t)t * BH, H, P.bp1, nullptr);
    grid_barrier(P.bar, tid, bid);
    p0 = n0; p1 = n1;
  }
}

// ---------------- final ys GEMM: out[b][t][:] = p[t][b] @ w2h (2-term) + bp2 ----------------
__global__ __launch_bounds__(256, 2) void proj_out_kernel(
    const ushort_t* __restrict__ pAh, const ushort_t* __restrict__ pAl,
    const ushort_t* __restrict__ w2h, const float* __restrict__ bp2,
    float* __restrict__ out, int n_pred)
{
  __shared__ char smem[49152];
  const int tid = threadIdx.x;
  const int rt = blockIdx.x >> 4;   // row-tile: 32 rows of [t][b]
  const int ct = blockIdx.x & 15;   // 32-col tile of LATENT
  phase_mm<2, 1, 1, 3, false>(smem, tid, rt, ct, true,
      pAh, pAl, H, H,
      w2h, nullptr,
      nullptr, nullptr, 0, 0, nullptr,
      nullptr, nullptr, nullptr, nullptr,
      nullptr, nullptr, n_pred, bp2, out);
}

// ---------------- fp32 fallback (round-1, known-good) ----------------

__global__ __launch_bounds__(256) void gru_cell_kernel(
    const float* __restrict__ x, int xs, int Kih,
    const float* __restrict__ h_prev,
    const float* __restrict__ wih, const float* __restrict__ whh,
    const float* __restrict__ bih, const float* __restrict__ bhh,
    float* __restrict__ h_out)
{
  __shared__ float Xs[32][33];
  __shared__ float Ws[48][33];
  const int tid = threadIdx.x;
  const int b0 = blockIdx.x * 32;
  const int j0 = blockIdx.y * 16;
  const int bg = tid & 15;
  const int jj = tid >> 4;
  const int j = j0 + jj;
  float accA[2][3];
  float accB[2][3];
  #pragma unroll
  for (int g = 0; g < 3; ++g) {
    const float bi = bih[g * H + j];
    const float bh = bhh[g * H + j];
    accA[0][g] = bi; accA[1][g] = bi;
    accB[0][g] = bh; accB[1][g] = bh;
  }
  for (int k0 = 0; k0 < Kih; k0 += 32) {
    {
      const int rr = tid >> 3, c4 = (tid & 7) << 2;
      const float4 v = *reinterpret_cast<const float4*>(&x[(size_t)(b0 + rr) * xs + k0 + c4]);
      Xs[rr][c4 + 0] = v.x; Xs[rr][c4 + 1] = v.y; Xs[rr][c4 + 2] = v.z; Xs[rr][c4 + 3] = v.w;
    }
    for (int li = tid; li < 48 * 8; li += 256) {
      const int rr = li >> 3, c4 = (li & 7) << 2;
      const int g = rr >> 4, jr = rr & 15;
      const float4 v = *reinterpret_cast<const float4*>(&wih[(size_t)(g * H + j0 + jr) * Kih + k0 + c4]);
      Ws[rr][c4 + 0] = v.x; Ws[rr][c4 + 1] = v.y; Ws[rr][c4 + 2] = v.z; Ws[rr][c4 + 3] = v.w;
    }
    __syncthreads();
    #pragma unroll
    for (int k = 0; k < 32; ++k) {
      const float x0 = Xs[bg][k];
      const float x1 = Xs[bg + 16][k];
      #pragma unroll
      for (int g = 0; g < 3; ++g) {
        const float wv = Ws[g * 16 + jj][k];
        accA[0][g] = fmaf(x0, wv, accA[0][g]);
        accA[1][g] = fmaf(x1, wv, accA[1][g]);
      }
    }
    __syncthreads();
  }
  for (int k0 = 0; k0 < H; k0 += 32) {
    {
      const int rr = tid >> 3, c4 = (tid & 7) << 2;
      const float4 v = *reinterpret_cast<const float4*>(&h_prev[(size_t)(b0 + rr) * H + k0 + c4]);
      Xs[rr][c4 + 0] = v.x; Xs[rr][c4 + 1] = v.y; Xs[rr][c4 + 2] = v.z; Xs[rr][c4 + 3] = v.w;
    }
    for (int li = tid; li < 48 * 8; li += 256) {
      const int rr = li >> 3, c4 = (li & 7) << 2;
      const int g = rr >> 4, jr = rr & 15;
      const float4 v = *reinterpret_cast<const float4*>(&whh[(size_t)(g * H + j0 + jr) * H + k0 + c4]);
      Ws[rr][c4 + 0] = v.x; Ws[rr][c4 + 1] = v.y; Ws[rr][c4 + 2] = v.z; Ws[rr][c4 + 3] = v.w;
    }
    __syncthreads();
    #pragma unroll
    for (int k = 0; k < 32; ++k) {
      const float h0v = Xs[bg][k];
      const float h1v = Xs[bg + 16][k];
      #pragma unroll
      for (int g = 0; g < 3; ++g) {
        const float wv = Ws[g * 16 + jj][k];
        accB[0][g] = fmaf(h0v, wv, accB[0][g]);
        accB[1][g] = fmaf(h1v, wv, accB[1][g]);
      }
    }
    __syncthreads();
  }
  #pragma unroll
  for (int i = 0; i < 2; ++i) {
    const int b = b0 + bg + i * 16;
    const float hp = h_prev[(size_t)b * H + j];
    const float r = sigmoidf_(accA[i][0] + accB[i][0]);
    const float z = sigmoidf_(accA[i][1] + accB[i][1]);
    const float n = tanhf(accA[i][2] + r * accB[i][2]);
    h_out[(size_t)b * H + j] = (1.0f - z) * n + z * hp;
  }
}

__global__ __launch_bounds__(256) void gemm_bias_kernel(
    const float* __restrict__ X, int xs, int K,
    const float* __restrict__ W, const float* __restrict__ bias,
    float* __restrict__ out1, int o1s,
    float* __restrict__ out2, int o2s,
    int relu)
{
  __shared__ float Xs[32][33];
  __shared__ float Ws[16][33];
  const int tid = threadIdx.x;
  const int b0 = blockIdx.x * 32;
  const int n0 = blockIdx.y * 16;
  const int bg = tid & 15;
  const int nn = tid >> 4;
  const int n = n0 + nn;
  float acc0 = bias[n];
  float acc1 = acc0;
  for (int k0 = 0; k0 < K; k0 += 32) {
    {
      const int rr = tid >> 3, c4 = (tid & 7) << 2;
      const float4 v = *reinterpret_cast<const float4*>(&X[(size_t)(b0 + rr) * xs + k0 + c4]);
      Xs[rr][c4 + 0] = v.x; Xs[rr][c4 + 1] = v.y; Xs[rr][c4 + 2] = v.z; Xs[rr][c4 + 3] = v.w;
    }
    if (tid < 128) {
      const int rr = tid >> 3, c4 = (tid & 7) << 2;
      const float4 v = *reinterpret_cast<const float4*>(&W[(size_t)(n0 + rr) * K + k0 + c4]);
      Ws[rr][c4 + 0] = v.x; Ws[rr][c4 + 1] = v.y; Ws[rr][c4 + 2] = v.z; Ws[rr][c4 + 3] = v.w;
    }
    __syncthreads();
    #pragma unroll
    for (int k = 0; k < 32; ++k) {
      const float wv = Ws[nn][k];
      acc0 = fmaf(Xs[bg][k], wv, acc0);
      acc1 = fmaf(Xs[bg + 16][k], wv, acc1);
    }
    __syncthreads();
  }
  if (relu) { acc0 = fmaxf(acc0, 0.0f); acc1 = fmaxf(acc1, 0.0f); }
  const int ba = b0 + bg, bb = b0 + bg + 16;
  out1[(size_t)ba * o1s + n] = acc0;
  out1[(size_t)bb * o1s + n] = acc1;
  if (out2 != nullptr) {
    out2[(size_t)ba * o2s + n] = acc0;
    out2[(size_t)bb * o2s + n] = acc1;
  }
}

// ---------------- host launch ----------------

extern "C" void kernel_launch(void* const* d_in, const int* in_sizes, int n_in,
                              void* d_out, int out_size, void* d_ws, size_t ws_size,
                              hipStream_t stream) {
  (void)n_in;
  const float* ctx  = (const float*)d_in[0];
  const float* wih0 = (const float*)d_in[1];
  const float* whh0 = (const float*)d_in[2];
  const float* bih0 = (const float*)d_in[3];
  const float* bhh0 = (const float*)d_in[4];
  const float* wih1 = (const float*)d_in[5];
  const float* whh1 = (const float*)d_in[6];
  const float* bih1 = (const float*)d_in[7];
  const float* bhh1 = (const float*)d_in[8];
  const float* w1   = (const float*)d_in[9];
  const float* bp1  = (const float*)d_in[10];
  const float* w2   = (const float*)d_in[11];
  const float* bp2  = (const float*)d_in[12];

  const int T_in   = in_sizes[0] / (B * LATENT);
  const int n_pred = out_size / (B * LATENT);
  float* out = (float*)d_out;

  // ---- ws layout ----
  size_t cur = 0;
  auto alloc = [&](size_t bytes) -> void* {
    void* p = (char*)d_ws + cur;
    cur += (bytes + 255) & ~(size_t)255;
    return p;
  };
  const int E_wih0 = 3 * H * LATENT, E_whh0 = 3 * H * H;
  const int E_wih1 = 3 * H * H, E_whh1 = 3 * H * H;
  const int E_w1 = H * H, E_w2 = LATENT * H;
  const int E_wf = 3 * H * H;
  const int E_ctx = in_sizes[0];

  ushort_t* wih0h = (ushort_t*)alloc(E_wih0 * 2);
  ushort_t* whh0h = (ushort_t*)alloc(E_whh0 * 2);
  ushort_t* wih1h = (ushort_t*)alloc(E_wih1 * 2);
  ushort_t* whh1h = (ushort_t*)alloc(E_whh1 * 2);
  ushort_t* w1h   = (ushort_t*)alloc(E_w1 * 2);
  ushort_t* w2h   = (ushort_t*)alloc(E_w2 * 2);
  ushort_t* wfh   = (ushort_t*)alloc((size_t)E_wf * 2);
  ushort_t* wfl   = (ushort_t*)alloc((size_t)E_wf * 2);
  ushort_t* ctxh  = (ushort_t*)alloc((size_t)E_ctx * 2);
  ushort_t* ctxl  = (ushort_t*)alloc((size_t)E_ctx * 2);
  ushort_t* h0Ahi = (ushort_t*)alloc((size_t)T_in * BH * 2);   // aliased as pA in decoder
  ushort_t* h0Alo = (ushort_t*)alloc((size_t)T_in * BH * 2);
  float* bf0 = (float*)alloc(3 * H * 4);
  size_t zero_start = cur;
  float* h0f[2]; float* h1f[2];
  ushort_t* h0hi[2]; ushort_t* h0lo[2]; ushort_t* h1hi[2]; ushort_t* h1lo[2];
  h0f[0] = (float*)alloc(BH * 4); h0f[1] = (float*)alloc(BH * 4);
  h1f[0] = (float*)alloc(BH * 4); h1f[1] = (float*)alloc(BH * 4);
  h0hi[0] = (ushort_t*)alloc(BH * 2); h0lo[0] = (ushort_t*)alloc(BH * 2);
  h0hi[1] = (ushort_t*)alloc(BH * 2); h0lo[1] = (ushort_t*)alloc(BH * 2);
  h1hi[0] = (ushort_t*)alloc(BH * 2); h1lo[0] = (ushort_t*)alloc(BH * 2);
  h1hi[1] = (ushort_t*)alloc(BH * 2); h1lo[1] = (ushort_t*)alloc(BH * 2);
  unsigned* bar = (unsigned*)alloc(16384);
  size_t zero_bytes = cur - zero_start;
  size_t required = cur;

  if (ws_size >= required && n_pred <= T_in) {
    auto splitA = [&](const float* s, ushort_t* hi, ushort_t* lo, int n) {
      int blocks = (n + 255) / 256; if (blocks > 2048) blocks = 2048;
      split_kernel<<<blocks, 256, 0, stream>>>(s, hi, lo, n);
    };
    auto splitW = [&](const float* s, ushort_t* hi, int n) {
      int blocks = (n + 255) / 256; if (blocks > 2048) blocks = 2048;
      split_hi_kernel<<<blocks, 256, 0, stream>>>(s, hi, n);
    };
    splitW(wih0, wih0h, E_wih0);
    splitW(whh0, whh0h, E_whh0);
    splitW(wih1, wih1h, E_wih1);
    splitW(whh1, whh1h, E_whh1);
    splitW(w1, w1h, E_w1);
    splitW(w2, w2h, E_w2);
    wf_kernel<<<dim3(3 * H / 32, H / 32), 256, 0, stream>>>(wih0, w2, wfh, wfl);
    bias_fuse_kernel<<<(3 * H + 255) / 256, 256, 0, stream>>>(wih0, bp2, bih0, bf0);
    splitA(ctx, ctxh, ctxl, E_ctx);
    {
      int n4 = (int)(zero_bytes / 16);
      zero4_kernel<<<2048, 256, 0, stream>>>((float4*)((char*)d_ws + zero_start), n4);
    }

    PParams P;
    P.ctxh = ctxh; P.ctxl = ctxl;
    P.wih0h = wih0h; P.whh0h = whh0h;
    P.wih1h = wih1h; P.whh1h = whh1h;
    P.w1h = w1h; P.wfh = wfh; P.wfl = wfl;
    P.bih0 = bih0; P.bhh0 = bhh0; P.bih1 = bih1; P.bhh1 = bhh1; P.bp1 = bp1;
    P.bf0 = bf0;
    P.h0f0 = h0f[0]; P.h0f1 = h0f[1]; P.h1f0 = h1f[0]; P.h1f1 = h1f[1];
    P.h0hi0 = h0hi[0]; P.h0lo0 = h0lo[0]; P.h0hi1 = h0hi[1]; P.h0lo1 = h0lo[1];
    P.h1hi0 = h1hi[0]; P.h1lo0 = h1lo[0]; P.h1hi1 = h1hi[1]; P.h1lo1 = h1lo[1];
    P.h0Ahi = h0Ahi; P.h0Alo = h0Alo;
    P.bar = bar;
    P.T_in = T_in; P.n_pred = n_pred; P.ctx_pitch = T_in * LATENT;

    gru_persistent<<<256, 256, 0, stream>>>(P);

    // final ys: out[b][t][:] = p[t][b] @ w2^T + bp2 (p stored in h0A alias)
    const int rowtiles = (n_pred * B) / 32;
    proj_out_kernel<<<rowtiles * 16, 256, 0, stream>>>(h0Ahi, h0Alo, w2h, bp2, out, n_pred);
    return;
  }

  // ---------- fp32 fallback path (round-1) ----------
  float* ws = (float*)d_ws;
  float* h0a = ws;
  float* h0b = h0a + (size_t)BH;
  float* h1a = h0b + (size_t)BH;
  float* h1b = h1a + (size_t)BH;
  float* p   = h1b + (size_t)BH;
  {
    int n4 = (4 * BH) / 4;
    zero4_kernel<<<256, 256, 0, stream>>>((float4*)h0a, n4);
  }
  float* y = p + (size_t)BH;
  float* h0p = h0a; float* h0n = h0b;
  float* h1p = h1a; float* h1n = h1b;
  const dim3 cgrid(4, 64);
  for (int t = 0; t < T_in; ++t) {
    const float* x = ctx + (size_t)t * LATENT;
    gru_cell_kernel<<<cgrid, 256, 0, stream>>>(x, T_in * LATENT, LATENT,
                                               h0p, wih0, whh0, bih0, bhh0, h0n);
    gru_cell_kernel<<<cgrid, 256, 0, stream>>>(h0n, H, H,
                                               h1p, wih1, whh1, bih1, bhh1, h1n);
    float* tmp;
    tmp = h0p; h0p = h0n; h0n = tmp;
    tmp = h1p; h1p = h1n; h1n = tmp;
  }
  for (int t = 0; t < n_pred; ++t) {
    const float* x; int xstride;
    if (t == 0) { x = ctx + (size_t)(T_in - 1) * LATENT; xstride = T_in * LATENT; }
    else        { x = y; xstride = LATENT; }
    gru_cell_kernel<<<cgrid, 256, 0, stream>>>(x, xstride, LATENT,
                                               h0p, wih0, whh0, bih0, bhh0, h0n);
    gru_cell_kernel<<<cgrid, 256, 0, stream>>>(h0n, H, H,
                                               h1p, wih1, whh1, bih1, bhh1, h1n);
    gemm_bias_kernel<<<dim3(4, H / 16), 256, 0, stream>>>(h1n, H, H, w1, bp1,
                                                          p, H, nullptr, 0, 1);
    gemm_bias_kernel<<<dim3(4, LATENT / 16), 256, 0, stream>>>(p, H, H, w2, bp2,
                                                               y, LATENT,
                                                               out + (size_t)t * LATENT,
                                                               n_pred * LATENT, 0);
    float* tmp;
    tmp = h0p; h0p = h0n; h0n = tmp;
    tmp = h1p; h1p = h1n; h1n = tmp;
  }
}

// Round 15
// 6559.611 us; speedup vs baseline: 1.2427x; 1.0179x over previous
//
#include <hip/hip_runtime.h>
#include <math.h>

#define B 128
#define LATENT 512
#define H 1024
#define BH (B * H)

typedef unsigned short ushort_t;
typedef unsigned int uint_t;
typedef __bf16 bf16x8 __attribute__((ext_vector_type(8)));
typedef float f32x4 __attribute__((ext_vector_type(4)));

// ---------------- common small kernels ----------------

__global__ __launch_bounds__(256) void zero4_kernel(float4* __restrict__ p, int n4) {
  int i = blockIdx.x * blockDim.x + threadIdx.x;
  int stride = gridDim.x * blockDim.x;
  float4 z = {0.f, 0.f, 0.f, 0.f};
  for (; i < n4; i += stride) p[i] = z;
}

__device__ __forceinline__ void split_bf16(float f, ushort_t& h, ushort_t& l) {
  uint_t u = __float_as_uint(f);
  uint_t hb = (u + 0x7FFFu + ((u >> 16) & 1u)) >> 16;
  float fh = __uint_as_float(hb << 16);
  float r = f - fh;
  uint_t v = __float_as_uint(r);
  uint_t lb = (v + 0x7FFFu + ((v >> 16) & 1u)) >> 16;
  h = (ushort_t)hb; l = (ushort_t)lb;
}

__global__ __launch_bounds__(256) void split_kernel(const float* __restrict__ src,
                                                    ushort_t* __restrict__ hi,
                                                    ushort_t* __restrict__ lo, int n) {
  int i = blockIdx.x * blockDim.x + threadIdx.x;
  int stride = gridDim.x * blockDim.x;
  for (; i < n; i += stride) {
    ushort_t h, l;
    split_bf16(src[i], h, l);
    hi[i] = h; lo[i] = l;
  }
}

__global__ __launch_bounds__(256) void split_hi_kernel(const float* __restrict__ src,
                                                       ushort_t* __restrict__ hi, int n) {
  int i = blockIdx.x * blockDim.x + threadIdx.x;
  int stride = gridDim.x * blockDim.x;
  for (; i < n; i += stride) {
    uint_t u = __float_as_uint(src[i]);
    hi[i] = (ushort_t)((u + 0x7FFFu + ((u >> 16) & 1u)) >> 16);
  }
}

// wf = wih0 @ w2  (fp32 GEMM, hi split).  [3H x 512] @ [512 x H] -> [3H x H]
__global__ __launch_bounds__(256) void wf_kernel(const float* __restrict__ wih0,
                                                 const float* __restrict__ w2,
                                                 ushort_t* __restrict__ wfh) {
  __shared__ float As[32][33];
  __shared__ float Bs[32][33];
  const int i0 = blockIdx.x * 32;
  const int k0 = blockIdx.y * 32;
  const int tid = threadIdx.x;
  const int r = tid >> 3, c4 = (tid & 7) << 2;
  float acc[4] = {0.f, 0.f, 0.f, 0.f};
  for (int m0 = 0; m0 < LATENT; m0 += 32) {
    {
      const float4 v = *reinterpret_cast<const float4*>(&wih0[(size_t)(i0 + r) * LATENT + m0 + c4]);
      As[r][c4] = v.x; As[r][c4 + 1] = v.y; As[r][c4 + 2] = v.z; As[r][c4 + 3] = v.w;
      const float4 w = *reinterpret_cast<const float4*>(&w2[(size_t)(m0 + r) * H + k0 + c4]);
      Bs[r][c4] = w.x; Bs[r][c4 + 1] = w.y; Bs[r][c4 + 2] = w.z; Bs[r][c4 + 3] = w.w;
    }
    __syncthreads();
    #pragma unroll
    for (int mm = 0; mm < 32; ++mm) {
      const float a = As[r][mm];
      #pragma unroll
      for (int x = 0; x < 4; ++x) acc[x] = fmaf(a, Bs[mm][c4 + x], acc[x]);
    }
    __syncthreads();
  }
  #pragma unroll
  for (int x = 0; x < 4; ++x) {
    uint_t u = __float_as_uint(acc[x]);
    wfh[(size_t)(i0 + r) * H + k0 + c4 + x] =
        (ushort_t)((u + 0x7FFFu + ((u >> 16) & 1u)) >> 16);
  }
}

// bf0[g] = bih0[g] + dot(wih0[g,:], bp2)
__global__ __launch_bounds__(256) void bias_fuse_kernel(const float* __restrict__ wih0,
                                                        const float* __restrict__ bp2,
                                                        const float* __restrict__ bih0,
                                                        float* __restrict__ bf0) {
  int g = blockIdx.x * blockDim.x + threadIdx.x;
  if (g < 3 * H) {
    float s = bih0[g];
    const float* row = wih0 + (size_t)g * LATENT;
    #pragma unroll 4
    for (int l = 0; l < LATENT; ++l) s = fmaf(row[l], bp2[l], s);
    bf0[g] = s;
  }
}

__device__ __forceinline__ float sigmoidf_(float v) { return 1.0f / (1.0f + expf(-v)); }

// ---------------- hierarchical grid barrier (round-6 form, known good) ----------------
__device__ __forceinline__ void grid_barrier(unsigned* bar, int tid, int bid) {
  __syncthreads();
  if (tid == 0) {
    const int g = bid & 7;
    unsigned* arr    = bar + (g << 6);
    unsigned* rel    = bar + 1024 + (g << 6);
    unsigned* master = bar + 2048;
    unsigned gen = __hip_atomic_load(rel, __ATOMIC_RELAXED, __HIP_MEMORY_SCOPE_AGENT);
    unsigned a = __hip_atomic_fetch_add(arr, 1u, __ATOMIC_ACQ_REL, __HIP_MEMORY_SCOPE_AGENT);
    if (a == 31u) {
      __hip_atomic_store(arr, 0u, __ATOMIC_RELAXED, __HIP_MEMORY_SCOPE_AGENT);
      unsigned m = __hip_atomic_fetch_add(master, 1u, __ATOMIC_ACQ_REL, __HIP_MEMORY_SCOPE_AGENT);
      if (m == 7u) {
        __hip_atomic_store(master, 0u, __ATOMIC_RELAXED, __HIP_MEMORY_SCOPE_AGENT);
        #pragma unroll
        for (int i = 0; i < 8; ++i)
          __hip_atomic_fetch_add(bar + 1024 + (i << 6), 1u, __ATOMIC_ACQ_REL, __HIP_MEMORY_SCOPE_AGENT);
      }
    }
    while (__hip_atomic_load(rel, __ATOMIC_RELAXED, __HIP_MEMORY_SCOPE_AGENT) == gen)
      __builtin_amdgcn_s_sleep(1);
    (void)__hip_atomic_load(rel, __ATOMIC_ACQUIRE, __HIP_MEMORY_SCOPE_AGENT);
  }
  __syncthreads();
}

// ---------------- one GEMM phase: 32 rows x NJ*16 cols x NG gates ----------------
// CHUNKW = K elems staged per chunk (128 or 256). 256-wide: 8KB slots, 2 staged
// issues/slot, wave k-slice 64 (2 MFMA k-substeps). Numerics: acc = xh@wh + xl@wh
// (+ xh@wl when WLO). EPI: 0=GRU gates, 1=relu+bias->split, 3=bias->scattered f32.
template <int NJ, int NG, int PH, int EPI, bool WLO, int CHUNKW>
__device__ __forceinline__ void phase_mm(
    char* smem, const int tid, const int Mb, const int jb, const bool active,
    const ushort_t* aAh, const ushort_t* aAl, int aApitch, int K1,
    const ushort_t* wAh, const ushort_t* wAl,
    const ushort_t* aBh, const ushort_t* aBl, int aBpitch, int K2,
    const ushort_t* wBh,
    const float* bih, const float* bhh,
    const float* h_prev, float* h_out,
    ushort_t* out_hi, ushort_t* out_lo, int split_pitch,
    const float* bias, float* out_f32)
{
  if (!active) return;
  constexpr int KST = CHUNKW / 128;      // k-substeps per chunk
  constexpr int SLOTB = CHUNKW * 32;     // bytes per slot (16 rows x CHUNKW x 2B)
  constexpr int NW = NJ * NG;
  constexpr int NSLOTA = 4 + NW * (WLO ? 2 : 1);
  constexpr int NSLOTB = 4 + NW;
  constexpr int BUFB = NSLOTA * SLOTB;
  constexpr int NPG = PH * NW;
  constexpr int CW = NJ * 16;
  constexpr int CSHIFT = (CHUNKW == 256) ? 8 : 7;

  const int b0 = Mb * 32;
  const int j0 = jb * CW;
  const int NC1 = K1 >> CSHIFT;
  const int NC2 = (PH == 2) ? (K2 >> CSHIFT) : 0;
  const int NC = NC1 + NC2;

  const char* g[NSLOTA];
  auto build = [&](const ushort_t* ah, const ushort_t* al, int apitch,
                   const ushort_t* wh, const ushort_t* wl, int K) {
    const int rowt = tid >> 4;
    const int cp = tid & 15;
    const int cc = cp ^ rowt;
    #pragma unroll
    for (int u = 0; u < NSLOTA; ++u) {
      const ushort_t* basep; size_t off;
      if (u < 2)      { basep = ah; off = (size_t)(b0 + u * 16 + rowt) * apitch + cc * 8; }
      else if (u < 4) { basep = al; off = (size_t)(b0 + (u - 2) * 16 + rowt) * apitch + cc * 8; }
      else if (u < 4 + NW) {
        const int w = u - 4, jt = w % NJ, gate = w / NJ;
        const int wrow = (NG == 3) ? (gate * H + j0 + jt * 16 + rowt) : (j0 + jt * 16 + rowt);
        basep = wh; off = (size_t)wrow * K + cc * 8;
      } else {
        const int w = u - 4 - NW, jt = w % NJ, gate = w / NJ;
        const int wrow = (NG == 3) ? (gate * H + j0 + jt * 16 + rowt) : (j0 + jt * 16 + rowt);
        basep = (wl != nullptr) ? wl : wh; off = (size_t)wrow * K + cc * 8;
      }
      g[u] = (const char*)(basep + off);
    }
  };

  // fragment read offsets per k-substep
  const int s = tid >> 6;
  const int q = (tid >> 4) & 3;
  const int r = tid & 15;
  int gsv[KST];
  #pragma unroll
  for (int k2 = 0; k2 < KST; ++k2) {
    const int G = s * (4 * KST) + k2 * 4 + q;     // granule 0..(16*KST-1)
    gsv[k2] = (G >> 4) * 4096 + ((G & 15) ^ r) * 16;
  }
  const int rbase = r * 256;

  f32x4 accA[NJ][NG][2];
  f32x4 accB[NJ][NG][2];
  #pragma unroll
  for (int jt = 0; jt < NJ; ++jt)
    #pragma unroll
    for (int gg = 0; gg < NG; ++gg)
      #pragma unroll
      for (int mf = 0; mf < 2; ++mf) {
        accA[jt][gg][mf] = (f32x4){0.f, 0.f, 0.f, 0.f};
        accB[jt][gg][mf] = (f32x4){0.f, 0.f, 0.f, 0.f};
      }

  const unsigned wofs = (unsigned)(tid >> 6) * 1024;
  auto issue = [&](int bsel, int koff, int nslot) {
    #pragma unroll
    for (int u = 0; u < NSLOTA; ++u) {
      if (u < nslot) {
        #pragma unroll
        for (int j = 0; j < KST; ++j) {
          __builtin_amdgcn_global_load_lds(
              (const __attribute__((address_space(1))) void*)(g[u] + koff + j * 256),
              (__attribute__((address_space(3))) void*)(smem + bsel * BUFB + u * SLOTB + j * 4096 + wofs),
              16, 0, 0);
        }
      }
    }
  };

  auto computeA = [&](int bsel) {
    const char* base = smem + bsel * BUFB;
    #pragma unroll
    for (int k2 = 0; k2 < KST; ++k2) {
      const int fo = rbase + gsv[k2];
      bf16x8 ah0 = *(const bf16x8*)(base + 0 * SLOTB + fo);
      bf16x8 ah1 = *(const bf16x8*)(base + 1 * SLOTB + fo);
      bf16x8 al0 = *(const bf16x8*)(base + 2 * SLOTB + fo);
      bf16x8 al1 = *(const bf16x8*)(base + 3 * SLOTB + fo);
      #pragma unroll
      for (int gg = 0; gg < NG; ++gg)
        #pragma unroll
        for (int jt = 0; jt < NJ; ++jt) {
          const int w = gg * NJ + jt;
          bf16x8 wh = *(const bf16x8*)(base + (4 + w) * SLOTB + fo);
          accA[jt][gg][0] = __builtin_amdgcn_mfma_f32_16x16x32_bf16(ah0, wh, accA[jt][gg][0], 0, 0, 0);
          if (WLO) {
            bf16x8 wl = *(const bf16x8*)(base + (4 + NW + w) * SLOTB + fo);
            accA[jt][gg][0] = __builtin_amdgcn_mfma_f32_16x16x32_bf16(ah0, wl, accA[jt][gg][0], 0, 0, 0);
            accA[jt][gg][1] = __builtin_amdgcn_mfma_f32_16x16x32_bf16(ah1, wl, accA[jt][gg][1], 0, 0, 0);
          }
          accA[jt][gg][0] = __builtin_amdgcn_mfma_f32_16x16x32_bf16(al0, wh, accA[jt][gg][0], 0, 0, 0);
          accA[jt][gg][1] = __builtin_amdgcn_mfma_f32_16x16x32_bf16(ah1, wh, accA[jt][gg][1], 0, 0, 0);
          accA[jt][gg][1] = __builtin_amdgcn_mfma_f32_16x16x32_bf16(al1, wh, accA[jt][gg][1], 0, 0, 0);
        }
    }
  };
  auto computeB = [&](int bsel) {
    const char* base = smem + bsel * BUFB;
    #pragma unroll
    for (int k2 = 0; k2 < KST; ++k2) {
      const int fo = rbase + gsv[k2];
      bf16x8 ah0 = *(const bf16x8*)(base + 0 * SLOTB + fo);
      bf16x8 ah1 = *(const bf16x8*)(base + 1 * SLOTB + fo);
      bf16x8 al0 = *(const bf16x8*)(base + 2 * SLOTB + fo);
      bf16x8 al1 = *(const bf16x8*)(base + 3 * SLOTB + fo);
      #pragma unroll
      for (int gg = 0; gg < NG; ++gg)
        #pragma unroll
        for (int jt = 0; jt < NJ; ++jt) {
          const int w = gg * NJ + jt;
          bf16x8 wh = *(const bf16x8*)(base + (4 + w) * SLOTB + fo);
          accB[jt][gg][0] = __builtin_amdgcn_mfma_f32_16x16x32_bf16(ah0, wh, accB[jt][gg][0], 0, 0, 0);
          accB[jt][gg][0] = __builtin_amdgcn_mfma_f32_16x16x32_bf16(al0, wh, accB[jt][gg][0], 0, 0, 0);
          accB[jt][gg][1] = __builtin_amdgcn_mfma_f32_16x16x32_bf16(ah1, wh, accB[jt][gg][1], 0, 0, 0);
          accB[jt][gg][1] = __builtin_amdgcn_mfma_f32_16x16x32_bf16(al1, wh, accB[jt][gg][1], 0, 0, 0);
        }
    }
  };

  // prologue
  build(aAh, aAl, aApitch, wAh, wAl, K1);
  issue(0, 0, NSLOTA);

  #pragma unroll 1
  for (int c = 0; c < NC; ++c) {
    __syncthreads();
    if (c + 1 < NC) {
      if (PH == 2 && c + 1 == NC1) {
        build(aBh, aBl, aBpitch, wBh, nullptr, K2);
        issue((c + 1) & 1, 0, NSLOTB);
      } else {
        const bool isB = (PH == 2) && (c + 1 >= NC1);
        const int koff = (isB ? (c + 1 - NC1) : (c + 1)) * (CHUNKW * 2);
        issue((c + 1) & 1, koff, isB ? NSLOTB : NSLOTA);
      }
    }
    if (PH == 1 || c < NC1) computeA(c & 1);
    else                    computeB(c & 1);
  }
  __syncthreads();

  // ---- cross-wave reduce (alias smem) ----
  const int lane = tid & 63;
  #pragma unroll
  for (int gg = 0; gg < NG; ++gg)
    #pragma unroll
    for (int jt = 0; jt < NJ; ++jt)
      #pragma unroll
      for (int mf = 0; mf < 2; ++mf) {
        const int w = gg * NJ + jt;
        *(f32x4*)(smem + (size_t)(((s * NPG + w) * 2 + mf) * 64 + lane) * 16) = accA[jt][gg][mf];
        if (PH == 2)
          *(f32x4*)(smem + (size_t)(((s * NPG + NW + w) * 2 + mf) * 64 + lane) * 16) = accB[jt][gg][mf];
      }
  __syncthreads();

  for (int o = tid; o < 32 * CW; o += 256) {
    const int row = o / CW, c = o % CW;
    const int jt = c >> 4, cr = c & 15;
    const int mf = row >> 4, br = row & 15, qq = br >> 2, rg = br & 3;
    const int ln = cr + qq * 16;
    float v[PH * NG];
    #pragma unroll
    for (int pg = 0; pg < PH * NG; ++pg) {
      const int w = (pg < NG) ? (pg * NJ + jt) : (NW + (pg - NG) * NJ + jt);
      float sum = 0.f;
      #pragma unroll
      for (int ss = 0; ss < 4; ++ss)
        sum += *(const float*)(smem + (size_t)(((ss * NPG + w) * 2 + mf) * 64 + ln) * 16 + rg * 4);
      v[pg] = sum;
    }
    const int bglob = b0 + row, jglob = j0 + c;
    if (EPI == 0) {
      float ir = v[0] + bih[jglob];
      float iz = v[1] + bih[H + jglob];
      float in_ = v[2] + bih[2 * H + jglob];
      float hr = v[3] + bhh[jglob];
      float hz = v[4] + bhh[H + jglob];
      float hn = v[5] + bhh[2 * H + jglob];
      float rr_ = sigmoidf_(ir + hr);
      float zz_ = sigmoidf_(iz + hz);
      float nn_ = tanhf(in_ + rr_ * hn);
      float hp = h_prev[(size_t)bglob * H + jglob];
      float ho = (1.f - zz_) * nn_ + zz_ * hp;
      h_out[(size_t)bglob * H + jglob] = ho;
      ushort_t hb, lb;
      split_bf16(ho, hb, lb);
      out_hi[(size_t)bglob * H + jglob] = hb;
      out_lo[(size_t)bglob * H + jglob] = lb;
    } else if (EPI == 1) {
      float vv = v[0] + bias[jglob];
      vv = fmaxf(vv, 0.f);
      ushort_t hb, lb;
      split_bf16(vv, hb, lb);
      out_hi[(size_t)bglob * split_pitch + jglob] = hb;
      out_lo[(size_t)bglob * split_pitch + jglob] = lb;
    } else {
      float vv = v[0] + bias[jglob];
      const int tt = bglob >> 7, bb2 = bglob & 127;
      out_f32[((size_t)bb2 * split_pitch + tt) * LATENT + jglob] = vv;
    }
  }
  __syncthreads();
}

// ---------------- persistent kernel: 65 enc + 192 dec phases ----------------

struct PParams {
  const ushort_t *ctxh, *ctxl;
  const ushort_t *wih0h, *whh0h;
  const ushort_t *wih1h, *whh1h;
  const ushort_t *w1h;
  const ushort_t *wfh;
  const float *bih0, *bhh0, *bih1, *bhh1, *bp1;
  const float *bf0;
  float *h0f0, *h0f1, *h1f0, *h1f1;
  ushort_t *h0hi0, *h0lo0, *h0hi1, *h0lo1;
  ushort_t *h1hi0, *h1lo0, *h1hi1, *h1lo1;
  ushort_t *h0Ahi, *h0Alo;      // [T_in][B][H]; aliased as pA in decoder
  unsigned* bar;
  int T_in, n_pred, ctx_pitch;
};

__global__ __launch_bounds__(256, 1) void gru_persistent(PParams P) {
  __shared__ char smem[114688];   // max(enc 2x40KB, dec 2x56KB)
  const int tid = threadIdx.x;
  const int bid = blockIdx.x;

  float* h0f[2] = {P.h0f0, P.h0f1};
  float* h1f[2] = {P.h1f0, P.h1f1};
  ushort_t* h0hi[2] = {P.h0hi0, P.h0hi1};
  ushort_t* h0lo[2] = {P.h0lo0, P.h0lo1};
  ushort_t* h1hi[2] = {P.h1hi0, P.h1hi1};
  ushort_t* h1lo[2] = {P.h1lo0, P.h1lo1};

  int p0 = 0, p1 = 0;

  // -------- pipelined encoder (CHUNKW=128, r14-identical) --------
  const int idx = (bid < 128) ? bid : (bid - 128);
  const int eMb = idx & 3;
  const int ejb = idx >> 2;
  #pragma unroll 1
  for (int p = 0; p <= P.T_in; ++p) {
    const int n0 = p0 ^ 1, n1 = p1 ^ 1;
    if (bid < 128) {
      if (p < P.T_in) {
        const int t = p;
        phase_mm<2, 3, 2, 0, false, 128>(smem, tid, eMb, ejb, true,
            P.ctxh + (size_t)t * LATENT, P.ctxl + (size_t)t * LATENT, P.ctx_pitch, LATENT,
            P.wih0h, nullptr,
            (t == 0) ? P.h0hi0 : P.h0Ahi + (size_t)(t - 1) * BH,
            (t == 0) ? P.h0lo0 : P.h0Alo + (size_t)(t - 1) * BH, H, H, P.whh0h,
            P.bih0, P.bhh0, h0f[p0], h0f[n0],
            P.h0Ahi + (size_t)t * BH, P.h0Alo + (size_t)t * BH, H, nullptr, nullptr);
      }
    } else {
      if (p >= 1) {
        const int t = p - 1;
        phase_mm<2, 3, 2, 0, false, 128>(smem, tid, eMb, ejb, true,
            P.h0Ahi + (size_t)t * BH, P.h0Alo + (size_t)t * BH, H, H,
            P.wih1h, nullptr,
            h1hi[p1], h1lo[p1], H, H, P.whh1h,
            P.bih1, P.bhh1, h1f[p1], h1f[n1],
            h1hi[n1], h1lo[n1], H, nullptr, nullptr);
      }
    }
    grid_barrier(P.bar, tid, bid);
    if (p < P.T_in) p0 = n0;
    if (p >= 1) p1 = n1;
  }

  // -------- decoder (CHUNKW=256): 3 phases/step {D0 fused, D1, DP} --------
  const int dMb = bid & 3;
  const int djb = bid >> 2;
  const ushort_t* d0ph = P.h0Ahi + (size_t)(P.T_in - 1) * BH;
  const ushort_t* d0pl = P.h0Alo + (size_t)(P.T_in - 1) * BH;
  ushort_t* pAh = P.h0Ahi;
  ushort_t* pAl = P.h0Alo;
  #pragma unroll 1
  for (int t = 0; t < P.n_pred; ++t) {
    const int n0 = p0 ^ 1;
    if (t == 0) {
      phase_mm<1, 3, 2, 0, false, 256>(smem, tid, dMb, djb, true,
          P.ctxh + (size_t)(P.T_in - 1) * LATENT, P.ctxl + (size_t)(P.T_in - 1) * LATENT,
          P.ctx_pitch, LATENT,
          P.wih0h, nullptr,
          d0ph, d0pl, H, H, P.whh0h,
          P.bih0, P.bhh0, h0f[p0], h0f[n0], h0hi[n0], h0lo[n0], H, nullptr, nullptr);
    } else {
      phase_mm<1, 3, 2, 0, false, 256>(smem, tid, dMb, djb, true,
          pAh + (size_t)(t - 1) * BH, pAl + (size_t)(t - 1) * BH, H, H,
          P.wfh, nullptr,
          d0ph, d0pl, H, H, P.whh0h,
          P.bf0, P.bhh0, h0f[p0], h0f[n0], h0hi[n0], h0lo[n0], H, nullptr, nullptr);
    }
    grid_barrier(P.bar, tid, bid);
    d0ph = h0hi[n0]; d0pl = h0lo[n0];
    const int n1 = p1 ^ 1;
    phase_mm<1, 3, 2, 0, false, 256>(smem, tid, dMb, djb, true,
        h0hi[n0], h0lo[n0], H, H,
        P.wih1h, nullptr,
        h1hi[p1], h1lo[p1], H, H, P.whh1h,
        P.bih1, P.bhh1, h1f[p1], h1f[n1], h1hi[n1], h1lo[n1], H, nullptr, nullptr);
    grid_barrier(P.bar, tid, bid);
    // p[t] = relu(h1 @ w1^T + bp1)
    phase_mm<1, 1, 1, 1, false, 256>(smem, tid, dMb, djb, true,
        h1hi[n1], h1lo[n1], H, H,
        P.w1h, nullptr,
        nullptr, nullptr, 0, 0, nullptr,
        nullptr, nullptr, nullptr, nullptr,
        pAh + (size_t)t * BH, pAl + (size_t)t * BH, H, P.bp1, nullptr);
    grid_barrier(P.bar, tid, bid);
    p0 = n0; p1 = n1;
  }
}

// ---------------- final ys GEMM (parallel, CHUNKW=128) ----------------
__global__ __launch_bounds__(256, 2) void proj_out_kernel(
    const ushort_t* __restrict__ pAh, const ushort_t* __restrict__ pAl,
    const ushort_t* __restrict__ w2h, const float* __restrict__ bp2,
    float* __restrict__ out, int n_pred)
{
  __shared__ char smem[49152];
  const int tid = threadIdx.x;
  const int rt = blockIdx.x >> 4;
  const int ct = blockIdx.x & 15;
  phase_mm<2, 1, 1, 3, false, 128>(smem, tid, rt, ct, true,
      pAh, pAl, H, H,
      w2h, nullptr,
      nullptr, nullptr, 0, 0, nullptr,
      nullptr, nullptr, nullptr, nullptr,
      nullptr, nullptr, n_pred, bp2, out);
}

// ---------------- fp32 fallback (round-1, known-good) ----------------

__global__ __launch_bounds__(256) void gru_cell_kernel(
    const float* __restrict__ x, int xs, int Kih,
    const float* __restrict__ h_prev,
    const float* __restrict__ wih, const float* __restrict__ whh,
    const float* __restrict__ bih, const float* __restrict__ bhh,
    float* __restrict__ h_out)
{
  __shared__ float Xs[32][33];
  __shared__ float Ws[48][33];
  const int tid = threadIdx.x;
  const int b0 = blockIdx.x * 32;
  const int j0 = blockIdx.y * 16;
  const int bg = tid & 15;
  const int jj = tid >> 4;
  const int j = j0 + jj;
  float accA[2][3];
  float accB[2][3];
  #pragma unroll
  for (int g = 0; g < 3; ++g) {
    const float bi = bih[g * H + j];
    const float bh = bhh[g * H + j];
    accA[0][g] = bi; accA[1][g] = bi;
    accB[0][g] = bh; accB[1][g] = bh;
  }
  for (int k0 = 0; k0 < Kih; k0 += 32) {
    {
      const int rr = tid >> 3, c4 = (tid & 7) << 2;
      const float4 v = *reinterpret_cast<const float4*>(&x[(size_t)(b0 + rr) * xs + k0 + c4]);
      Xs[rr][c4 + 0] = v.x; Xs[rr][c4 + 1] = v.y; Xs[rr][c4 + 2] = v.z; Xs[rr][c4 + 3] = v.w;
    }
    for (int li = tid; li < 48 * 8; li += 256) {
      const int rr = li >> 3, c4 = (li & 7) << 2;
      const int g = rr >> 4, jr = rr & 15;
      const float4 v = *reinterpret_cast<const float4*>(&wih[(size_t)(g * H + j0 + jr) * Kih + k0 + c4]);
      Ws[rr][c4 + 0] = v.x; Ws[rr][c4 + 1] = v.y; Ws[rr][c4 + 2] = v.z; Ws[rr][c4 + 3] = v.w;
    }
    __syncthreads();
    #pragma unroll
    for (int k = 0; k < 32; ++k) {
      const float x0 = Xs[bg][k];
      const float x1 = Xs[bg + 16][k];
      #pragma unroll
      for (int g = 0; g < 3; ++g) {
        const float wv = Ws[g * 16 + jj][k];
        accA[0][g] = fmaf(x0, wv, accA[0][g]);
        accA[1][g] = fmaf(x1, wv, accA[1][g]);
      }
    }
    __syncthreads();
  }
  for (int k0 = 0; k0 < H; k0 += 32) {
    {
      const int rr = tid >> 3, c4 = (tid & 7) << 2;
      const float4 v = *reinterpret_cast<const float4*>(&h_prev[(size_t)(b0 + rr) * H + k0 + c4]);
      Xs[rr][c4 + 0] = v.x; Xs[rr][c4 + 1] = v.y; Xs[rr][c4 + 2] = v.z; Xs[rr][c4 + 3] = v.w;
    }
    for (int li = tid; li < 48 * 8; li += 256) {
      const int rr = li >> 3, c4 = (li & 7) << 2;
      const int g = rr >> 4, jr = rr & 15;
      const float4 v = *reinterpret_cast<const float4*>(&whh[(size_t)(g * H + j0 + jr) * H + k0 + c4]);
      Ws[rr][c4 + 0] = v.x; Ws[rr][c4 + 1] = v.y; Ws[rr][c4 + 2] = v.z; Ws[rr][c4 + 3] = v.w;
    }
    __syncthreads();
    #pragma unroll
    for (int k = 0; k < 32; ++k) {
      const float h0v = Xs[bg][k];
      const float h1v = Xs[bg + 16][k];
      #pragma unroll
      for (int g = 0; g < 3; ++g) {
        const float wv = Ws[g * 16 + jj][k];
        accB[0][g] = fmaf(h0v, wv, accB[0][g]);
        accB[1][g] = fmaf(h1v, wv, accB[1][g]);
      }
    }
    __syncthreads();
  }
  #pragma unroll
  for (int i = 0; i < 2; ++i) {
    const int b = b0 + bg + i * 16;
    const float hp = h_prev[(size_t)b * H + j];
    const float r = sigmoidf_(accA[i][0] + accB[i][0]);
    const float z = sigmoidf_(accA[i][1] + accB[i][1]);
    const float n = tanhf(accA[i][2] + r * accB[i][2]);
    h_out[(size_t)b * H + j] = (1.0f - z) * n + z * hp;
  }
}

__global__ __launch_bounds__(256) void gemm_bias_kernel(
    const float* __restrict__ X, int xs, int K,
    const float* __restrict__ W, const float* __restrict__ bias,
    float* __restrict__ out1, int o1s,
    float* __restrict__ out2, int o2s,
    int relu)
{
  __shared__ float Xs[32][33];
  __shared__ float Ws[16][33];
  const int tid = threadIdx.x;
  const int b0 = blockIdx.x * 32;
  const int n0 = blockIdx.y * 16;
  const int bg = tid & 15;
  const int nn = tid >> 4;
  const int n = n0 + nn;
  float acc0 = bias[n];
  float acc1 = acc0;
  for (int k0 = 0; k0 < K; k0 += 32) {
    {
      const int rr = tid >> 3, c4 = (tid & 7) << 2;
      const float4 v = *reinterpret_cast<const float4*>(&X[(size_t)(b0 + rr) * xs + k0 + c4]);
      Xs[rr][c4 + 0] = v.x; Xs[rr][c4 + 1] = v.y; Xs[rr][c4 + 2] = v.z; Xs[rr][c4 + 3] = v.w;
    }
    if (tid < 128) {
      const int rr = tid >> 3, c4 = (tid & 7) << 2;
      const float4 v = *reinterpret_cast<const float4*>(&W[(size_t)(n0 + rr) * K + k0 + c4]);
      Ws[rr][c4 + 0] = v.x; Ws[rr][c4 + 1] = v.y; Ws[rr][c4 + 2] = v.z; Ws[rr][c4 + 3] = v.w;
    }
    __syncthreads();
    #pragma unroll
    for (int k = 0; k < 32; ++k) {
      const float wv = Ws[nn][k];
      acc0 = fmaf(Xs[bg][k], wv, acc0);
      acc1 = fmaf(Xs[bg + 16][k], wv, acc1);
    }
    __syncthreads();
  }
  if (relu) { acc0 = fmaxf(acc0, 0.0f); acc1 = fmaxf(acc1, 0.0f); }
  const int ba = b0 + bg, bb = b0 + bg + 16;
  out1[(size_t)ba * o1s + n] = acc0;
  out1[(size_t)bb * o1s + n] = acc1;
  if (out2 != nullptr) {
    out2[(size_t)ba * o2s + n] = acc0;
    out2[(size_t)bb * o2s + n] = acc1;
  }
}

// ---------------- host launch ----------------

extern "C" void kernel_launch(void* const* d_in, const int* in_sizes, int n_in,
                              void* d_out, int out_size, void* d_ws, size_t ws_size,
                              hipStream_t stream) {
  (void)n_in;
  const float* ctx  = (const float*)d_in[0];
  const float* wih0 = (const float*)d_in[1];
  const float* whh0 = (const float*)d_in[2];
  const float* bih0 = (const float*)d_in[3];
  const float* bhh0 = (const float*)d_in[4];
  const float* wih1 = (const float*)d_in[5];
  const float* whh1 = (const float*)d_in[6];
  const float* bih1 = (const float*)d_in[7];
  const float* bhh1 = (const float*)d_in[8];
  const float* w1   = (const float*)d_in[9];
  const float* bp1  = (const float*)d_in[10];
  const float* w2   = (const float*)d_in[11];
  const float* bp2  = (const float*)d_in[12];

  const int T_in   = in_sizes[0] / (B * LATENT);
  const int n_pred = out_size / (B * LATENT);
  float* out = (float*)d_out;

  // ---- ws layout ----
  size_t cur = 0;
  auto alloc = [&](size_t bytes) -> void* {
    void* p = (char*)d_ws + cur;
    cur += (bytes + 255) & ~(size_t)255;
    return p;
  };
  const int E_wih0 = 3 * H * LATENT, E_whh0 = 3 * H * H;
  const int E_wih1 = 3 * H * H, E_whh1 = 3 * H * H;
  const int E_w1 = H * H, E_w2 = LATENT * H;
  const int E_wf = 3 * H * H;
  const int E_ctx = in_sizes[0];

  ushort_t* wih0h = (ushort_t*)alloc(E_wih0 * 2);
  ushort_t* whh0h = (ushort_t*)alloc(E_whh0 * 2);
  ushort_t* wih1h = (ushort_t*)alloc(E_wih1 * 2);
  ushort_t* whh1h = (ushort_t*)alloc(E_whh1 * 2);
  ushort_t* w1h   = (ushort_t*)alloc(E_w1 * 2);
  ushort_t* w2h   = (ushort_t*)alloc(E_w2 * 2);
  ushort_t* wfh   = (ushort_t*)alloc((size_t)E_wf * 2);
  ushort_t* ctxh  = (ushort_t*)alloc((size_t)E_ctx * 2);
  ushort_t* ctxl  = (ushort_t*)alloc((size_t)E_ctx * 2);
  ushort_t* h0Ahi = (ushort_t*)alloc((size_t)T_in * BH * 2);
  ushort_t* h0Alo = (ushort_t*)alloc((size_t)T_in * BH * 2);
  float* bf0 = (float*)alloc(3 * H * 4);
  size_t zero_start = cur;
  float* h0f[2]; float* h1f[2];
  ushort_t* h0hi[2]; ushort_t* h0lo[2]; ushort_t* h1hi[2]; ushort_t* h1lo[2];
  h0f[0] = (float*)alloc(BH * 4); h0f[1] = (float*)alloc(BH * 4);
  h1f[0] = (float*)alloc(BH * 4); h1f[1] = (float*)alloc(BH * 4);
  h0hi[0] = (ushort_t*)alloc(BH * 2); h0lo[0] = (ushort_t*)alloc(BH * 2);
  h0hi[1] = (ushort_t*)alloc(BH * 2); h0lo[1] = (ushort_t*)alloc(BH * 2);
  h1hi[0] = (ushort_t*)alloc(BH * 2); h1lo[0] = (ushort_t*)alloc(BH * 2);
  h1hi[1] = (ushort_t*)alloc(BH * 2); h1lo[1] = (ushort_t*)alloc(BH * 2);
  unsigned* bar = (unsigned*)alloc(16384);
  size_t zero_bytes = cur - zero_start;
  size_t required = cur;

  if (ws_size >= required && n_pred <= T_in) {
    auto splitA = [&](const float* s, ushort_t* hi, ushort_t* lo, int n) {
      int blocks = (n + 255) / 256; if (blocks > 2048) blocks = 2048;
      split_kernel<<<blocks, 256, 0, stream>>>(s, hi, lo, n);
    };
    auto splitW = [&](const float* s, ushort_t* hi, int n) {
      int blocks = (n + 255) / 256; if (blocks > 2048) blocks = 2048;
      split_hi_kernel<<<blocks, 256, 0, stream>>>(s, hi, n);
    };
    splitW(wih0, wih0h, E_wih0);
    splitW(whh0, whh0h, E_whh0);
    splitW(wih1, wih1h, E_wih1);
    splitW(whh1, whh1h, E_whh1);
    splitW(w1, w1h, E_w1);
    splitW(w2, w2h, E_w2);
    wf_kernel<<<dim3(3 * H / 32, H / 32), 256, 0, stream>>>(wih0, w2, wfh);
    bias_fuse_kernel<<<(3 * H + 255) / 256, 256, 0, stream>>>(wih0, bp2, bih0, bf0);
    splitA(ctx, ctxh, ctxl, E_ctx);
    {
      int n4 = (int)(zero_bytes / 16);
      zero4_kernel<<<2048, 256, 0, stream>>>((float4*)((char*)d_ws + zero_start), n4);
    }

    PParams P;
    P.ctxh = ctxh; P.ctxl = ctxl;
    P.wih0h = wih0h; P.whh0h = whh0h;
    P.wih1h = wih1h; P.whh1h = whh1h;
    P.w1h = w1h; P.wfh = wfh;
    P.bih0 = bih0; P.bhh0 = bhh0; P.bih1 = bih1; P.bhh1 = bhh1; P.bp1 = bp1;
    P.bf0 = bf0;
    P.h0f0 = h0f[0]; P.h0f1 = h0f[1]; P.h1f0 = h1f[0]; P.h1f1 = h1f[1];
    P.h0hi0 = h0hi[0]; P.h0lo0 = h0lo[0]; P.h0hi1 = h0hi[1]; P.h0lo1 = h0lo[1];
    P.h1hi0 = h1hi[0]; P.h1lo0 = h1lo[0]; P.h1hi1 = h1hi[1]; P.h1lo1 = h1lo[1];
    P.h0Ahi = h0Ahi; P.h0Alo = h0Alo;
    P.bar = bar;
    P.T_in = T_in; P.n_pred = n_pred; P.ctx_pitch = T_in * LATENT;

    gru_persistent<<<256, 256, 0, stream>>>(P);

    const int rowtiles = (n_pred * B) / 32;
    proj_out_kernel<<<rowtiles * 16, 256, 0, stream>>>(h0Ahi, h0Alo, w2h, bp2, out, n_pred);
    return;
  }

  // ---------- fp32 fallback path (round-1) ----------
  float* ws = (float*)d_ws;
  float* h0a = ws;
  float* h0b = h0a + (size_t)BH;
  float* h1a = h0b + (size_t)BH;
  float* h1b = h1a + (size_t)BH;
  float* p   = h1b + (size_t)BH;
  {
    int n4 = (4 * BH) / 4;
    zero4_kernel<<<256, 256, 0, stream>>>((float4*)h0a, n4);
  }
  float* y = p + (size_t)BH;
  float* h0p = h0a; float* h0n = h0b;
  float* h1p = h1a; float* h1n = h1b;
  const dim3 cgrid(4, 64);
  for (int t = 0; t < T_in; ++t) {
    const float* x = ctx + (size_t)t * LATENT;
    gru_cell_kernel<<<cgrid, 256, 0, stream>>>(x, T_in * LATENT, LATENT,
                                               h0p, wih0, whh0, bih0, bhh0, h0n);
    gru_cell_kernel<<<cgrid, 256, 0, stream>>>(h0n, H, H,
                                               h1p, wih1, whh1, bih1, bhh1, h1n);
    float* tmp;
    tmp = h0p; h0p = h0n; h0n = tmp;
    tmp = h1p; h1p = h1n; h1n = tmp;
  }
  for (int t = 0; t < n_pred; ++t) {
    const float* x; int xstride;
    if (t == 0) { x = ctx + (size_t)(T_in - 1) * LATENT; xstride = T_in * LATENT; }
    else        { x = y; xstride = LATENT; }
    gru_cell_kernel<<<cgrid, 256, 0, stream>>>(x, xstride, LATENT,
                                               h0p, wih0, whh0, bih0, bhh0, h0n);
    gru_cell_kernel<<<cgrid, 256, 0, stream>>>(h0n, H, H,
                                               h1p, wih1, whh1, bih1, bhh1, h1n);
    gemm_bias_kernel<<<dim3(4, H / 16), 256, 0, stream>>>(h1n, H, H, w1, bp1,
                                                          p, H, nullptr, 0, 1);
    gemm_bias_kernel<<<dim3(4, LATENT / 16), 256, 0, stream>>>(p, H, H, w2, bp2,
                                                               y, LATENT,
                                                               out + (size_t)t * LATENT,
                                                               n_pred * LATENT, 0);
    float* tmp;
    tmp = h0p; h0p = h0n; h0n = tmp;
    tmp = h1p; h1p = h1n; h1n = tmp;
  }
}